// Round 4
// baseline (1063.477 us; speedup 1.0000x reference)
//
#include <hip/hip_runtime.h>
#include <hip/hip_bf16.h>

#define N_ROWS 32768
#define DDIM   256
#define KCODES 8192
#define QZ     (N_ROWS * DDIM)
#define NTILES 128            // 8192 codes / 64 per tile
#define MARGIN 1.25f          // ~17 sigma of hi*hi approx-error diff

typedef __attribute__((ext_vector_type(8))) short short8;
typedef __attribute__((ext_vector_type(4))) float f32x4;

__device__ __forceinline__ unsigned short f2bf(float f) {   // RNE float->bf16
  unsigned u = __builtin_bit_cast(unsigned, f);
  u += 0x7FFFu + ((u >> 16) & 1u);
  return (unsigned short)(u >> 16);
}

// insert distance d (code c) into per-row top-3 state (b1<=b2<=b3)
__device__ __forceinline__ void ins(float& b1, float& b2, float& b3, int& i1, int& i2,
                                    float d, int c) {
  bool l3 = d < b3, l2 = d < b2, l1 = d < b1;
  b3 = l3 ? (l2 ? b2 : d) : b3;
  b2 = l2 ? (l1 ? b1 : d) : b2;
  i2 = l2 ? (l1 ? i1 : c) : i2;
  b1 = l1 ? d : b1;
  i1 = l1 ? c : i1;
}

// merge sorted triple (o1<=o2<=o3, idx y1,y2) into (a1<=a2<=a3, idx x1,x2)
__device__ __forceinline__ void merge3(float& a1, float& a2, float& a3, int& x1, int& x2,
                                       float o1, float o2, float o3, int y1, int y2) {
  bool oW = o1 < a1;
  float mx1 = oW ? a1 : o1;  int mxi = oW ? x1 : y1;
  float n1  = oW ? o1 : a1;  int ni1 = oW ? y1 : x1;
  bool lA = a2 < o2;
  float lo2 = lA ? a2 : o2;  int li2 = lA ? x2 : y2;
  float hi2 = lA ? o2 : a2;
  bool m2w = mx1 < lo2;
  float n2 = m2w ? mx1 : lo2; int ni2 = m2w ? mxi : li2;
  float n3 = fminf(fminf(fmaxf(mx1, lo2), hi2), fminf(a3, o3));
  a1 = n1; a2 = n2; a3 = n3; x1 = ni1; x2 = ni2;
}

// ---- cnorm only (fallback path) ----
__global__ __launch_bounds__(256) void vq_cnorm(const float* __restrict__ cb,
                                                float* __restrict__ cn) {
  int n = blockIdx.x * 4 + (threadIdx.x >> 6);
  int lane = threadIdx.x & 63;
  float4 c4 = *reinterpret_cast<const float4*>(cb + (size_t)n * DDIM + lane * 4);
  double s = (double)c4.x * c4.x + (double)c4.y * c4.y +
             (double)c4.z * c4.z + (double)c4.w * c4.w;
  #pragma unroll
  for (int off = 32; off > 0; off >>= 1) s += __shfl_down(s, off, 64);
  if (lane == 0) cn[n] = (float)s;
}

// ---- prep: codebook -> swizzled bf16 HI rows (512B/code) + cnorm ----
// logical 16B unit u of code n stored at n*512 + (u ^ (n&7))*16
__global__ __launch_bounds__(256) void vq_prep(const float* __restrict__ cb,
                                               unsigned char* __restrict__ wcb,
                                               float* __restrict__ cn) {
  int n = blockIdx.x * 4 + (threadIdx.x >> 6);
  int lane = threadIdx.x & 63;
  float4 c4 = *reinterpret_cast<const float4*>(cb + (size_t)n * DDIM + lane * 4);
  double s = (double)c4.x * c4.x + (double)c4.y * c4.y +
             (double)c4.z * c4.z + (double)c4.w * c4.w;
  #pragma unroll
  for (int off = 32; off > 0; off >>= 1) s += __shfl_down(s, off, 64);
  if (lane == 0) cn[n] = (float)s;

  unsigned short h0 = f2bf(c4.x), h1 = f2bf(c4.y), h2 = f2bf(c4.z), h3 = f2bf(c4.w);
  size_t base = (size_t)n * 512 +
                (size_t)((((lane >> 1) ^ (n & 7)) << 4) + (lane & 1) * 8);
  *reinterpret_cast<ushort4*>(wcb + base) = make_ushort4(h0, h1, h2, h3);
}

// ---- main MFMA kernel: 256 blocks x 512 thr; block = 128 rows x full K sweep ----
// waves: 4 wm x 2 wn; wave tile = 32 rows (2 mfrags) x 32 codes (2 nfrags); A = hi-only bf16
__global__ __launch_bounds__(512, 1) void vq_mfma(
    const float* __restrict__ z, const unsigned char* __restrict__ wcb,
    const float* __restrict__ cn, const float* __restrict__ cb,
    float* __restrict__ out,
    int* __restrict__ cntA, int4* __restrict__ rowsA,
    int* __restrict__ cntB, int* __restrict__ rowsB) {
  __shared__ __align__(16) unsigned char cs[2][32768];   // 64 codes x 512B, double buffer
  __shared__ float rb1[2][128], rb2[2][128], rb3[2][128];
  __shared__ int   ri1[2][128], ri2[2][128];
  __shared__ int   sIdx[128];

  const int tid = threadIdx.x;
  const int w = tid >> 6, lane = tid & 63;
  const int wm = w >> 1, wn = w & 1;
  const int g = lane >> 4, l15 = lane & 15;

  // A fragments: hi-only bf16, 2 mfrags x 8 dc = 64 VGPR, resident whole kernel
  short8 zh[2][8];
  const int rA = blockIdx.x * 128 + wm * 32 + l15;
  #pragma unroll
  for (int mf = 0; mf < 2; ++mf) {
    #pragma unroll
    for (int dc = 0; dc < 8; ++dc) {
      const float* zp = z + (size_t)(rA + mf * 16) * DDIM + dc * 32 + g * 8;
      float4 f0 = *reinterpret_cast<const float4*>(zp);
      float4 f1 = *reinterpret_cast<const float4*>(zp + 4);
      short8 hh;
      hh[0] = (short)f2bf(f0.x); hh[1] = (short)f2bf(f0.y);
      hh[2] = (short)f2bf(f0.z); hh[3] = (short)f2bf(f0.w);
      hh[4] = (short)f2bf(f1.x); hh[5] = (short)f2bf(f1.y);
      hh[6] = (short)f2bf(f1.z); hh[7] = (short)f2bf(f1.w);
      zh[mf][dc] = hh;
    }
  }

  // per-row-slot top-3 (8 slots = 2 mf x 4 acc rows)
  float b1[8], b2[8], b3[8];
  int i1[8], i2[8];
  #pragma unroll
  for (int s = 0; s < 8; ++s) { b1[s] = 3.4e38f; b2[s] = 3.4e38f; b3[s] = 3.4e38f; i1[s] = 0; i2[s] = 0; }

  // stage tile 0 (32KB: 512 thr x 4 x 16B, wave-linear dest, pre-swizzled src)
  #pragma unroll
  for (int i = 0; i < 4; ++i) {
    __builtin_amdgcn_global_load_lds(
        (const __attribute__((address_space(1))) void*)(wcb + tid * 16 + i * 8192),
        (__attribute__((address_space(3))) void*)(&cs[0][tid * 16 + i * 8192]), 16, 0, 0);
  }
  __syncthreads();

  const int cc0 = wn * 32 + l15;          // code-in-tile, nfrag 0
  const int cc1 = cc0 + 16;               // nfrag 1 (same &7)
  const int swz = cc0 & 7;

  for (int nt = 0; nt < NTILES; ++nt) {
    const int cur = nt & 1;
    if (nt + 1 < NTILES) {                // async prefetch next tile
      const unsigned char* gsrc = wcb + (size_t)(nt + 1) * 32768;
      #pragma unroll
      for (int i = 0; i < 4; ++i) {
        __builtin_amdgcn_global_load_lds(
            (const __attribute__((address_space(1))) void*)(gsrc + tid * 16 + i * 8192),
            (__attribute__((address_space(3))) void*)(&cs[cur ^ 1][tid * 16 + i * 8192]), 16, 0, 0);
      }
    }

    int code0 = nt * 64 + cc0;
    float cn0 = cn[code0];                 // L2-hot, coalesced across l15
    float cn1 = cn[code0 + 16];

    const unsigned char* lb = cs[cur];
    f32x4 a00 = {0.f, 0.f, 0.f, 0.f}, a01 = a00, a10 = a00, a11 = a00;
    #pragma unroll
    for (int dc = 0; dc < 8; ++dc) {
      int u = dc * 4 + g;
      int o0 = cc0 * 512 + ((u ^ swz) << 4);
      int o1 = cc1 * 512 + ((u ^ swz) << 4);
      short8 c0 = *reinterpret_cast<const short8*>(lb + o0);
      short8 c1 = *reinterpret_cast<const short8*>(lb + o1);
      a00 = __builtin_amdgcn_mfma_f32_16x16x32_bf16(zh[0][dc], c0, a00, 0, 0, 0);
      a01 = __builtin_amdgcn_mfma_f32_16x16x32_bf16(zh[0][dc], c1, a01, 0, 0, 0);
      a10 = __builtin_amdgcn_mfma_f32_16x16x32_bf16(zh[1][dc], c0, a10, 0, 0, 0);
      a11 = __builtin_amdgcn_mfma_f32_16x16x32_bf16(zh[1][dc], c1, a11, 0, 0, 0);
    }

    #pragma unroll
    for (int mf = 0; mf < 2; ++mf) {
      const f32x4 an0 = mf ? a10 : a00;
      const f32x4 an1 = mf ? a11 : a01;
      #pragma unroll
      for (int r = 0; r < 4; ++r) {
        const int s = mf * 4 + r;
        float d0 = fmaf(-2.0f, an0[r], cn0);
        ins(b1[s], b2[s], b3[s], i1[s], i2[s], d0, code0);
        float d1 = fmaf(-2.0f, an1[r], cn1);
        ins(b1[s], b2[s], b3[s], i1[s], i2[s], d1, code0 + 16);
      }
    }
    __syncthreads();   // cur reads done; prefetch drained (compiler vmcnt before barrier)
  }

  // intra-wave merge across the 16 code-lanes
  #pragma unroll
  for (int s = 0; s < 8; ++s) {
    float B1 = b1[s], B2 = b2[s], B3 = b3[s];
    int I1 = i1[s], I2 = i2[s];
    #pragma unroll
    for (int m = 1; m <= 8; m <<= 1) {
      float o1 = __shfl_xor(B1, m, 64), o2 = __shfl_xor(B2, m, 64), o3 = __shfl_xor(B3, m, 64);
      int y1 = __shfl_xor(I1, m, 64), y2 = __shfl_xor(I2, m, 64);
      merge3(B1, B2, B3, I1, I2, o1, o2, o3, y1, y2);
    }
    if (l15 == 0) {
      int row = wm * 32 + (s >> 2) * 16 + g * 4 + (s & 3);
      rb1[wn][row] = B1; rb2[wn][row] = B2; rb3[wn][row] = B3;
      ri1[wn][row] = I1; ri2[wn][row] = I2;
    }
  }
  __syncthreads();

  // merge the 2 wn copies, write index, flag tight rows
  if (tid < 128) {
    float B1 = rb1[0][tid], B2 = rb2[0][tid], B3 = rb3[0][tid];
    int I1 = ri1[0][tid], I2 = ri2[0][tid];
    merge3(B1, B2, B3, I1, I2, rb1[1][tid], rb2[1][tid], rb3[1][tid], ri1[1][tid], ri2[1][tid]);
    int grow = blockIdx.x * 128 + tid;
    out[QZ + grow] = (float)I1;
    sIdx[tid] = I1;
    if (B3 - B1 < MARGIN) {                    // >2 contenders: full exact sweep
      int p = atomicAdd(cntB, 1);
      rowsB[p] = grow;
    } else if (B2 - B1 < MARGIN) {             // 2 contenders: exact pair check
      int p = atomicAdd(cntA, 1);
      rowsA[p] = make_int4(grow, I1, I2, 0);
    }
  }
  __syncthreads();

  // gather q_z = codebook[idx]
  #pragma unroll
  for (int i = 0; i < 16; ++i) {
    int f = tid + i * 512;
    int r = f >> 6, c4i = f & 63;
    float4 v = *reinterpret_cast<const float4*>(cb + (size_t)sIdx[r] * DDIM + c4i * 4);
    *reinterpret_cast<float4*>(&out[(size_t)(blockIdx.x * 128 + r) * DDIM + c4i * 4]) = v;
  }
}

// ---- cleanup A: exact fp32 compare of top-2 candidates per flagged row ----
__global__ __launch_bounds__(256) void vq_pairs(
    const float* __restrict__ z, const float* __restrict__ cb, const float* __restrict__ cn,
    float* __restrict__ out, const int* __restrict__ cntA, const int4* __restrict__ rowsA) {
  int n = *cntA;
  int lane = threadIdx.x & 63;
  for (int e = blockIdx.x * 4 + (threadIdx.x >> 6); e < n; e += gridDim.x * 4) {
    int4 ent = rowsA[e];
    int row = ent.x, c1 = ent.y, c2 = ent.z;
    float4 zv = *reinterpret_cast<const float4*>(z + (size_t)row * DDIM + lane * 4);
    float4 a = *reinterpret_cast<const float4*>(cb + (size_t)c1 * DDIM + lane * 4);
    float4 b = *reinterpret_cast<const float4*>(cb + (size_t)c2 * DDIM + lane * 4);
    float p1 = zv.x * a.x + zv.y * a.y + zv.z * a.z + zv.w * a.w;
    float p2 = zv.x * b.x + zv.y * b.y + zv.z * b.z + zv.w * b.w;
    #pragma unroll
    for (int m = 1; m <= 32; m <<= 1) { p1 += __shfl_xor(p1, m, 64); p2 += __shfl_xor(p2, m, 64); }
    float d1 = cn[c1] - 2.0f * p1;
    float d2 = cn[c2] - 2.0f * p2;
    int win = (d2 < d1 || (d2 == d1 && c2 < c1)) ? c2 : c1;
    if (lane == 0) out[QZ + row] = (float)win;
    float4 cw = *reinterpret_cast<const float4*>(cb + (size_t)win * DDIM + lane * 4);
    *reinterpret_cast<float4*>(&out[(size_t)row * DDIM + lane * 4]) = cw;
  }
}

// ---- cleanup B: exact fp32 full-codebook argmin, one flagged row per block ----
__global__ __launch_bounds__(256) void vq_fullsweep(
    const float* __restrict__ z, const float* __restrict__ cb, const float* __restrict__ cn,
    float* __restrict__ out, const int* __restrict__ cntB, const int* __restrict__ rowsB) {
  __shared__ float zrow[DDIM];
  __shared__ unsigned long long wred[4];
  __shared__ int skmin;
  int nB = *cntB;
  for (int fi = blockIdx.x; fi < nB; fi += gridDim.x) {
    int row = rowsB[fi];
    __syncthreads();
    if (threadIdx.x < 64)
      *reinterpret_cast<float4*>(&zrow[threadIdx.x * 4]) =
          *reinterpret_cast<const float4*>(z + (size_t)row * DDIM + threadIdx.x * 4);
    __syncthreads();
    unsigned long long bkey = ~0ULL;
    for (int j = 0; j < 32; ++j) {
      int k = threadIdx.x + j * 256;
      const float* cp = cb + (size_t)k * DDIM;
      float acc = 0.f;
      #pragma unroll 8
      for (int d4 = 0; d4 < 64; ++d4) {
        float4 a = *reinterpret_cast<const float4*>(&zrow[d4 * 4]);
        float4 c4 = *reinterpret_cast<const float4*>(cp + d4 * 4);
        acc = fmaf(a.x, c4.x, acc); acc = fmaf(a.y, c4.y, acc);
        acc = fmaf(a.z, c4.z, acc); acc = fmaf(a.w, c4.w, acc);
      }
      float d = cn[k] - 2.0f * acc;
      unsigned m = __builtin_bit_cast(unsigned, d);
      m = (m >> 31) ? ~m : (m | 0x80000000u);
      unsigned long long key = ((unsigned long long)m << 32) | (unsigned)k;
      bkey = (key < bkey) ? key : bkey;
    }
    #pragma unroll
    for (int m2 = 1; m2 <= 32; m2 <<= 1) {
      unsigned long long o = __shfl_xor(bkey, m2, 64);
      bkey = (o < bkey) ? o : bkey;
    }
    if ((threadIdx.x & 63) == 0) wred[threadIdx.x >> 6] = bkey;
    __syncthreads();
    if (threadIdx.x == 0) {
      unsigned long long kk = wred[0];
      for (int q = 1; q < 4; ++q) kk = (wred[q] < kk) ? wred[q] : kk;
      int ki = (int)(kk & 0xFFFFFFFFULL);
      skmin = ki;
      out[QZ + row] = (float)ki;
    }
    __syncthreads();
    int ki = skmin;
    if (threadIdx.x < 64)
      *reinterpret_cast<float4*>(&out[(size_t)row * DDIM + threadIdx.x * 4]) =
          *reinterpret_cast<const float4*>(cb + (size_t)ki * DDIM + threadIdx.x * 4);
    __syncthreads();
  }
}

// ---- round-1 fp32 fallback (only if ws too small) ----
#define FB_BM 64
#define FB_BK 32
#define FB_LD 260
__global__ __launch_bounds__(256) void vq_main_fb(const float* __restrict__ z,
                                                  const float* __restrict__ cb,
                                                  const float* __restrict__ cn,
                                                  float* __restrict__ out) {
  __shared__ float zs[FB_BM * FB_LD];
  __shared__ float csh[FB_BK * FB_LD];
  __shared__ float redd[FB_BM][16];
  __shared__ int   redi[FB_BM][16];
  __shared__ int   sidx[FB_BM];
  const int t = threadIdx.x;
  const int row0 = blockIdx.x * FB_BM;
  #pragma unroll
  for (int i = 0; i < 16; ++i) {
    int f = t + i * 256; int r = f >> 6, c4 = f & 63;
    *reinterpret_cast<float4*>(&zs[r * FB_LD + c4 * 4]) =
        *reinterpret_cast<const float4*>(z + (size_t)(row0 + r) * DDIM + c4 * 4);
  }
  const int tr = t >> 4, tc = t & 15;
  float best[4]; int bidx[4];
  #pragma unroll
  for (int i = 0; i < 4; ++i) { best[i] = 3.4e38f; bidx[i] = 0; }
  for (int kt = 0; kt < KCODES; kt += FB_BK) {
    __syncthreads();
    #pragma unroll
    for (int i = 0; i < 8; ++i) {
      int f = t + i * 256; int r = f >> 6, c4 = f & 63;
      *reinterpret_cast<float4*>(&csh[r * FB_LD + c4 * 4]) =
          *reinterpret_cast<const float4*>(cb + (size_t)(kt + r) * DDIM + c4 * 4);
    }
    __syncthreads();
    float acc[4][2] = {{0.f,0.f},{0.f,0.f},{0.f,0.f},{0.f,0.f}};
    #pragma unroll 8
    for (int d4 = 0; d4 < 64; ++d4) {
      float4 b0 = *reinterpret_cast<const float4*>(&csh[tc * FB_LD + d4 * 4]);
      float4 b1v = *reinterpret_cast<const float4*>(&csh[(tc + 16) * FB_LD + d4 * 4]);
      #pragma unroll
      for (int i = 0; i < 4; ++i) {
        float4 a = *reinterpret_cast<const float4*>(&zs[(4 * tr + i) * FB_LD + d4 * 4]);
        acc[i][0] = fmaf(a.x, b0.x, acc[i][0]); acc[i][0] = fmaf(a.y, b0.y, acc[i][0]);
        acc[i][0] = fmaf(a.z, b0.z, acc[i][0]); acc[i][0] = fmaf(a.w, b0.w, acc[i][0]);
        acc[i][1] = fmaf(a.x, b1v.x, acc[i][1]); acc[i][1] = fmaf(a.y, b1v.y, acc[i][1]);
        acc[i][1] = fmaf(a.z, b1v.z, acc[i][1]); acc[i][1] = fmaf(a.w, b1v.w, acc[i][1]);
      }
    }
    float cn0 = cn[kt + tc], cn1 = cn[kt + tc + 16];
    #pragma unroll
    for (int i = 0; i < 4; ++i) {
      float d0 = cn0 - 2.0f * acc[i][0];
      if (d0 < best[i]) { best[i] = d0; bidx[i] = kt + tc; }
      float d1 = cn1 - 2.0f * acc[i][1];
      if (d1 < best[i]) { best[i] = d1; bidx[i] = kt + tc + 16; }
    }
  }
  #pragma unroll
  for (int i = 0; i < 4; ++i) { redd[4 * tr + i][tc] = best[i]; redi[4 * tr + i][tc] = bidx[i]; }
  __syncthreads();
  if (t < FB_BM) {
    float bd = redd[t][0]; int bi = redi[t][0];
    #pragma unroll
    for (int j = 1; j < 16; ++j) {
      float d = redd[t][j]; int ix = redi[t][j];
      if (d < bd || (d == bd && ix < bi)) { bd = d; bi = ix; }
    }
    sidx[t] = bi;
    out[QZ + row0 + t] = (float)bi;
  }
  __syncthreads();
  #pragma unroll
  for (int i = 0; i < 16; ++i) {
    int f = t + i * 256; int r = f >> 6, c4 = f & 63;
    *reinterpret_cast<float4*>(&out[(size_t)(row0 + r) * DDIM + c4 * 4]) =
        *reinterpret_cast<const float4*>(cb + (size_t)sidx[r] * DDIM + c4 * 4);
  }
}

extern "C" void kernel_launch(void* const* d_in, const int* in_sizes, int n_in,
                              void* d_out, int out_size, void* d_ws, size_t ws_size,
                              hipStream_t stream) {
  const float* z  = (const float*)d_in[0];
  const float* cb = (const float*)d_in[1];
  float* out = (float*)d_out;

  const size_t OFF_CN  = (size_t)KCODES * 512;           // 4 MiB wcb
  const size_t OFF_CNT = OFF_CN + (size_t)KCODES * 4;    // cntA @+0, cntB @+4
  const size_t OFF_RA  = OFF_CNT + 16;
  const size_t OFF_RB  = OFF_RA + (size_t)N_ROWS * 16;
  const size_t NEED    = OFF_RB + (size_t)N_ROWS * 4;

  if (ws_size >= NEED) {
    unsigned char* wcb = (unsigned char*)d_ws;
    float* cn = (float*)(wcb + OFF_CN);
    int* cntA = (int*)(wcb + OFF_CNT);
    int* cntB = (int*)(wcb + OFF_CNT + 4);
    int4* rowsA = (int4*)(wcb + OFF_RA);
    int* rowsB = (int*)(wcb + OFF_RB);
    hipMemsetAsync(cntA, 0, 8, stream);
    vq_prep<<<KCODES / 4, 256, 0, stream>>>(cb, wcb, cn);
    vq_mfma<<<N_ROWS / 128, 512, 0, stream>>>(z, wcb, cn, cb, out,
                                              cntA, rowsA, cntB, rowsB);
    vq_pairs<<<128, 256, 0, stream>>>(z, cb, cn, out, cntA, rowsA);
    vq_fullsweep<<<512, 256, 0, stream>>>(z, cb, cn, out, cntB, rowsB);
  } else {
    float* cn = (float*)d_ws;
    vq_cnorm<<<KCODES / 4, 256, 0, stream>>>(cb, cn);
    vq_main_fb<<<N_ROWS / FB_BM, 256, 0, stream>>>(z, cb, cn, out);
  }
}

// Round 5
// 1038.899 us; speedup vs baseline: 1.0237x; 1.0237x over previous
//
#include <hip/hip_runtime.h>
#include <hip/hip_bf16.h>

#define N_ROWS 32768
#define DDIM   256
#define KCODES 8192
#define QZ     (N_ROWS * DDIM)
#define NTILES 128            // 8192 codes / 64 per tile
#define MARGIN 1.25f          // ~17 sigma of hi*hi approx-error diff

typedef __attribute__((ext_vector_type(8))) short short8;
typedef __attribute__((ext_vector_type(4))) float f32x4;

__device__ __forceinline__ unsigned short f2bf(float f) {   // RNE float->bf16
  unsigned u = __builtin_bit_cast(unsigned, f);
  u += 0x7FFFu + ((u >> 16) & 1u);
  return (unsigned short)(u >> 16);
}

// insert distance d (code c) into per-row top-3 state (b1<=b2<=b3)
__device__ __forceinline__ void ins(float& b1, float& b2, float& b3, int& i1, int& i2,
                                    float d, int c) {
  bool l3 = d < b3, l2 = d < b2, l1 = d < b1;
  b3 = l3 ? (l2 ? b2 : d) : b3;
  b2 = l2 ? (l1 ? b1 : d) : b2;
  i2 = l2 ? (l1 ? i1 : c) : i2;
  b1 = l1 ? d : b1;
  i1 = l1 ? c : i1;
}

// merge sorted triple (o1<=o2<=o3, idx y1,y2) into (a1<=a2<=a3, idx x1,x2)
__device__ __forceinline__ void merge3(float& a1, float& a2, float& a3, int& x1, int& x2,
                                       float o1, float o2, float o3, int y1, int y2) {
  bool oW = o1 < a1;
  float mx1 = oW ? a1 : o1;  int mxi = oW ? x1 : y1;
  float n1  = oW ? o1 : a1;  int ni1 = oW ? y1 : x1;
  bool lA = a2 < o2;
  float lo2 = lA ? a2 : o2;  int li2 = lA ? x2 : y2;
  float hi2 = lA ? o2 : a2;
  bool m2w = mx1 < lo2;
  float n2 = m2w ? mx1 : lo2; int ni2 = m2w ? mxi : li2;
  float n3 = fminf(fminf(fmaxf(mx1, lo2), hi2), fminf(a3, o3));
  a1 = n1; a2 = n2; a3 = n3; x1 = ni1; x2 = ni2;
}

// ---- cnorm only (fallback path) ----
__global__ __launch_bounds__(256) void vq_cnorm(const float* __restrict__ cb,
                                                float* __restrict__ cn) {
  int n = blockIdx.x * 4 + (threadIdx.x >> 6);
  int lane = threadIdx.x & 63;
  float4 c4 = *reinterpret_cast<const float4*>(cb + (size_t)n * DDIM + lane * 4);
  double s = (double)c4.x * c4.x + (double)c4.y * c4.y +
             (double)c4.z * c4.z + (double)c4.w * c4.w;
  #pragma unroll
  for (int off = 32; off > 0; off >>= 1) s += __shfl_down(s, off, 64);
  if (lane == 0) cn[n] = (float)s;
}

// ---- prep: codebook -> swizzled bf16 HI rows (512B/code) + cnorm ----
// logical 16B unit u of code n stored at n*512 + (u ^ (n&7))*16
__global__ __launch_bounds__(256) void vq_prep(const float* __restrict__ cb,
                                               unsigned char* __restrict__ wcb,
                                               float* __restrict__ cn) {
  int n = blockIdx.x * 4 + (threadIdx.x >> 6);
  int lane = threadIdx.x & 63;
  float4 c4 = *reinterpret_cast<const float4*>(cb + (size_t)n * DDIM + lane * 4);
  double s = (double)c4.x * c4.x + (double)c4.y * c4.y +
             (double)c4.z * c4.z + (double)c4.w * c4.w;
  #pragma unroll
  for (int off = 32; off > 0; off >>= 1) s += __shfl_down(s, off, 64);
  if (lane == 0) cn[n] = (float)s;

  unsigned short h0 = f2bf(c4.x), h1 = f2bf(c4.y), h2 = f2bf(c4.z), h3 = f2bf(c4.w);
  size_t base = (size_t)n * 512 +
                (size_t)((((lane >> 1) ^ (n & 7)) << 4) + (lane & 1) * 8);
  *reinterpret_cast<ushort4*>(wcb + base) = make_ushort4(h0, h1, h2, h3);
}

// ---- main MFMA kernel: 256 blocks x 512 thr; block = 128 rows x full K sweep ----
// waves: 4 wm x 2 wn; wave tile = 32 rows (2 mfrags) x 32 codes (2 nfrags); A = hi-only bf16
__global__ __launch_bounds__(512, 1) void vq_mfma(
    const float* __restrict__ z, const unsigned char* __restrict__ wcb,
    const float* __restrict__ cn, const float* __restrict__ cb,
    float* __restrict__ out,
    int* __restrict__ cntA, int4* __restrict__ rowsA,
    int* __restrict__ cntB, int* __restrict__ rowsB) {
  __shared__ __align__(16) unsigned char cs[2][32768];   // 64 codes x 512B, double buffer
  __shared__ float rb1[2][128], rb2[2][128], rb3[2][128];
  __shared__ int   ri1[2][128], ri2[2][128];
  __shared__ int   sIdx[128];

  const int tid = threadIdx.x;
  const int w = tid >> 6, lane = tid & 63;
  const int wm = w >> 1, wn = w & 1;
  const int g = lane >> 4, l15 = lane & 15;

  // A fragments: hi-only bf16, 2 mfrags x 8 dc = 64 VGPR, resident whole kernel
  short8 zh[2][8];
  const int rA = blockIdx.x * 128 + wm * 32 + l15;
  #pragma unroll
  for (int mf = 0; mf < 2; ++mf) {
    #pragma unroll
    for (int dc = 0; dc < 8; ++dc) {
      const float* zp = z + (size_t)(rA + mf * 16) * DDIM + dc * 32 + g * 8;
      float4 f0 = *reinterpret_cast<const float4*>(zp);
      float4 f1 = *reinterpret_cast<const float4*>(zp + 4);
      short8 hh;
      hh[0] = (short)f2bf(f0.x); hh[1] = (short)f2bf(f0.y);
      hh[2] = (short)f2bf(f0.z); hh[3] = (short)f2bf(f0.w);
      hh[4] = (short)f2bf(f1.x); hh[5] = (short)f2bf(f1.y);
      hh[6] = (short)f2bf(f1.z); hh[7] = (short)f2bf(f1.w);
      zh[mf][dc] = hh;
    }
  }

  // per-row-slot top-3 (8 slots = 2 mf x 4 acc rows)
  float b1[8], b2[8], b3[8];
  int i1[8], i2[8];
  #pragma unroll
  for (int s = 0; s < 8; ++s) { b1[s] = 3.4e38f; b2[s] = 3.4e38f; b3[s] = 3.4e38f; i1[s] = 0; i2[s] = 0; }

  // stage tile 0 (32KB: 512 thr x 4 x 16B, wave-linear dest, pre-swizzled src)
  #pragma unroll
  for (int i = 0; i < 4; ++i) {
    __builtin_amdgcn_global_load_lds(
        (const __attribute__((address_space(1))) void*)(wcb + tid * 16 + i * 8192),
        (__attribute__((address_space(3))) void*)(&cs[0][tid * 16 + i * 8192]), 16, 0, 0);
  }
  __syncthreads();

  const int cc0 = wn * 32 + l15;          // code-in-tile, nfrag 0
  const int cc1 = cc0 + 16;               // nfrag 1 (same &7)
  const int swz = cc0 & 7;

  for (int nt = 0; nt < NTILES; ++nt) {
    const int cur = nt & 1;
    if (nt + 1 < NTILES) {                // async prefetch next tile
      const unsigned char* gsrc = wcb + (size_t)(nt + 1) * 32768;
      #pragma unroll
      for (int i = 0; i < 4; ++i) {
        __builtin_amdgcn_global_load_lds(
            (const __attribute__((address_space(1))) void*)(gsrc + tid * 16 + i * 8192),
            (__attribute__((address_space(3))) void*)(&cs[cur ^ 1][tid * 16 + i * 8192]), 16, 0, 0);
      }
    }

    int code0 = nt * 64 + cc0;
    float cn0 = cn[code0];                 // L2-hot, coalesced across l15
    float cn1 = cn[code0 + 16];

    const unsigned char* lb = cs[cur];
    f32x4 a00 = {0.f, 0.f, 0.f, 0.f}, a01 = a00, a10 = a00, a11 = a00;
    #pragma unroll
    for (int dc = 0; dc < 8; ++dc) {
      int u = dc * 4 + g;
      int o0 = cc0 * 512 + ((u ^ swz) << 4);
      int o1 = cc1 * 512 + ((u ^ swz) << 4);
      short8 c0 = *reinterpret_cast<const short8*>(lb + o0);
      short8 c1 = *reinterpret_cast<const short8*>(lb + o1);
      a00 = __builtin_amdgcn_mfma_f32_16x16x32_bf16(zh[0][dc], c0, a00, 0, 0, 0);
      a01 = __builtin_amdgcn_mfma_f32_16x16x32_bf16(zh[0][dc], c1, a01, 0, 0, 0);
      a10 = __builtin_amdgcn_mfma_f32_16x16x32_bf16(zh[1][dc], c0, a10, 0, 0, 0);
      a11 = __builtin_amdgcn_mfma_f32_16x16x32_bf16(zh[1][dc], c1, a11, 0, 0, 0);
    }

    #pragma unroll
    for (int mf = 0; mf < 2; ++mf) {
      const f32x4 an0 = mf ? a10 : a00;
      const f32x4 an1 = mf ? a11 : a01;
      #pragma unroll
      for (int r = 0; r < 4; ++r) {
        const int s = mf * 4 + r;
        float d0 = fmaf(-2.0f, an0[r], cn0);
        ins(b1[s], b2[s], b3[s], i1[s], i2[s], d0, code0);
        float d1 = fmaf(-2.0f, an1[r], cn1);
        ins(b1[s], b2[s], b3[s], i1[s], i2[s], d1, code0 + 16);
      }
    }
    __syncthreads();   // cur reads done; prefetch drained (compiler vmcnt before barrier)
  }

  // intra-wave merge across the 16 code-lanes
  #pragma unroll
  for (int s = 0; s < 8; ++s) {
    float B1 = b1[s], B2 = b2[s], B3 = b3[s];
    int I1 = i1[s], I2 = i2[s];
    #pragma unroll
    for (int m = 1; m <= 8; m <<= 1) {
      float o1 = __shfl_xor(B1, m, 64), o2 = __shfl_xor(B2, m, 64), o3 = __shfl_xor(B3, m, 64);
      int y1 = __shfl_xor(I1, m, 64), y2 = __shfl_xor(I2, m, 64);
      merge3(B1, B2, B3, I1, I2, o1, o2, o3, y1, y2);
    }
    if (l15 == 0) {
      int row = wm * 32 + (s >> 2) * 16 + g * 4 + (s & 3);
      rb1[wn][row] = B1; rb2[wn][row] = B2; rb3[wn][row] = B3;
      ri1[wn][row] = I1; ri2[wn][row] = I2;
    }
  }
  __syncthreads();

  // merge the 2 wn copies, write index, flag tight rows
  if (tid < 128) {
    float B1 = rb1[0][tid], B2 = rb2[0][tid], B3 = rb3[0][tid];
    int I1 = ri1[0][tid], I2 = ri2[0][tid];
    merge3(B1, B2, B3, I1, I2, rb1[1][tid], rb2[1][tid], rb3[1][tid], ri1[1][tid], ri2[1][tid]);
    int grow = blockIdx.x * 128 + tid;
    out[QZ + grow] = (float)I1;
    sIdx[tid] = I1;
    if (B3 - B1 < MARGIN) {                    // >2 contenders: full exact sweep
      int p = atomicAdd(cntB, 1);
      rowsB[p] = grow;
    } else if (B2 - B1 < MARGIN) {             // 2 contenders: exact pair check
      int p = atomicAdd(cntA, 1);
      rowsA[p] = make_int4(grow, I1, I2, 0);
    }
  }
  __syncthreads();

  // gather q_z = codebook[idx]
  #pragma unroll
  for (int i = 0; i < 16; ++i) {
    int f = tid + i * 512;
    int r = f >> 6, c4i = f & 63;
    float4 v = *reinterpret_cast<const float4*>(cb + (size_t)sIdx[r] * DDIM + c4i * 4);
    *reinterpret_cast<float4*>(&out[(size_t)(blockIdx.x * 128 + r) * DDIM + c4i * 4]) = v;
  }
}

// ---- cleanup A: exact fp32 compare of top-2 candidates per flagged row ----
__global__ __launch_bounds__(256) void vq_pairs(
    const float* __restrict__ z, const float* __restrict__ cb, const float* __restrict__ cn,
    float* __restrict__ out, const int* __restrict__ cntA, const int4* __restrict__ rowsA) {
  int n = *cntA;
  int lane = threadIdx.x & 63;
  for (int e = blockIdx.x * 4 + (threadIdx.x >> 6); e < n; e += gridDim.x * 4) {
    int4 ent = rowsA[e];
    int row = ent.x, c1 = ent.y, c2 = ent.z;
    float4 zv = *reinterpret_cast<const float4*>(z + (size_t)row * DDIM + lane * 4);
    float4 a = *reinterpret_cast<const float4*>(cb + (size_t)c1 * DDIM + lane * 4);
    float4 b = *reinterpret_cast<const float4*>(cb + (size_t)c2 * DDIM + lane * 4);
    float p1 = zv.x * a.x + zv.y * a.y + zv.z * a.z + zv.w * a.w;
    float p2 = zv.x * b.x + zv.y * b.y + zv.z * b.z + zv.w * b.w;
    #pragma unroll
    for (int m = 1; m <= 32; m <<= 1) { p1 += __shfl_xor(p1, m, 64); p2 += __shfl_xor(p2, m, 64); }
    float d1 = cn[c1] - 2.0f * p1;
    float d2 = cn[c2] - 2.0f * p2;
    int win = (d2 < d1 || (d2 == d1 && c2 < c1)) ? c2 : c1;
    if (lane == 0) out[QZ + row] = (float)win;
    float4 cw = *reinterpret_cast<const float4*>(cb + (size_t)win * DDIM + lane * 4);
    *reinterpret_cast<float4*>(&out[(size_t)row * DDIM + lane * 4]) = cw;
  }
}

// ---- cleanup B: exact fp32 full-codebook argmin, COALESCED wave-per-code ----
// One row per block iteration; wave w sweeps codes [w*2048, (w+1)*2048).
// Lane l holds the code row's dims [4l, 4l+4) -> float4 load is a perfectly
// coalesced 1KB wave transaction. Dot via 6-level shfl_xor butterfly.
__global__ __launch_bounds__(256) void vq_fullsweep(
    const float* __restrict__ z, const float* __restrict__ cb, const float* __restrict__ cn,
    float* __restrict__ out, const int* __restrict__ cntB, const int* __restrict__ rowsB) {
  __shared__ float zrow[DDIM];
  __shared__ unsigned long long wred[4];
  __shared__ int skmin;
  int nB = *cntB;
  const int w = threadIdx.x >> 6, lane = threadIdx.x & 63;
  for (int fi = blockIdx.x; fi < nB; fi += gridDim.x) {
    int row = rowsB[fi];
    __syncthreads();
    if (threadIdx.x < 64)
      *reinterpret_cast<float4*>(&zrow[threadIdx.x * 4]) =
          *reinterpret_cast<const float4*>(z + (size_t)row * DDIM + threadIdx.x * 4);
    __syncthreads();
    const float4 za = *reinterpret_cast<const float4*>(&zrow[lane * 4]);
    unsigned long long bkey = ~0ULL;
    for (int j = 0; j < 2048; j += 2) {
      const int k0 = w * 2048 + j;
      const float4 c0 = *reinterpret_cast<const float4*>(cb + (size_t)k0 * DDIM + lane * 4);
      const float4 c1 = *reinterpret_cast<const float4*>(cb + (size_t)(k0 + 1) * DDIM + lane * 4);
      float p0 = za.x * c0.x + za.y * c0.y + za.z * c0.z + za.w * c0.w;
      float p1 = za.x * c1.x + za.y * c1.y + za.z * c1.z + za.w * c1.w;
      #pragma unroll
      for (int m = 1; m <= 32; m <<= 1) {
        p0 += __shfl_xor(p0, m, 64);
        p1 += __shfl_xor(p1, m, 64);
      }
      float d0 = cn[k0] - 2.0f * p0;
      float d1 = cn[k0 + 1] - 2.0f * p1;
      unsigned m0 = __builtin_bit_cast(unsigned, d0);
      m0 = (m0 >> 31) ? ~m0 : (m0 | 0x80000000u);
      unsigned m1 = __builtin_bit_cast(unsigned, d1);
      m1 = (m1 >> 31) ? ~m1 : (m1 | 0x80000000u);
      unsigned long long k0k = ((unsigned long long)m0 << 32) | (unsigned)k0;
      unsigned long long k1k = ((unsigned long long)m1 << 32) | (unsigned)(k0 + 1);
      bkey = (k0k < bkey) ? k0k : bkey;
      bkey = (k1k < bkey) ? k1k : bkey;
    }
    // all lanes of a wave hold identical bkey after the full butterfly
    if (lane == 0) wred[w] = bkey;
    __syncthreads();
    if (threadIdx.x == 0) {
      unsigned long long kk = wred[0];
      #pragma unroll
      for (int q = 1; q < 4; ++q) kk = (wred[q] < kk) ? wred[q] : kk;
      int ki = (int)(kk & 0xFFFFFFFFULL);
      skmin = ki;
      out[QZ + row] = (float)ki;
    }
    __syncthreads();
    int ki = skmin;
    if (threadIdx.x < 64)
      *reinterpret_cast<float4*>(&out[(size_t)row * DDIM + threadIdx.x * 4]) =
          *reinterpret_cast<const float4*>(cb + (size_t)ki * DDIM + threadIdx.x * 4);
    __syncthreads();
  }
}

// ---- round-1 fp32 fallback (only if ws too small) ----
#define FB_BM 64
#define FB_BK 32
#define FB_LD 260
__global__ __launch_bounds__(256) void vq_main_fb(const float* __restrict__ z,
                                                  const float* __restrict__ cb,
                                                  const float* __restrict__ cn,
                                                  float* __restrict__ out) {
  __shared__ float zs[FB_BM * FB_LD];
  __shared__ float csh[FB_BK * FB_LD];
  __shared__ float redd[FB_BM][16];
  __shared__ int   redi[FB_BM][16];
  __shared__ int   sidx[FB_BM];
  const int t = threadIdx.x;
  const int row0 = blockIdx.x * FB_BM;
  #pragma unroll
  for (int i = 0; i < 16; ++i) {
    int f = t + i * 256; int r = f >> 6, c4 = f & 63;
    *reinterpret_cast<float4*>(&zs[r * FB_LD + c4 * 4]) =
        *reinterpret_cast<const float4*>(z + (size_t)(row0 + r) * DDIM + c4 * 4);
  }
  const int tr = t >> 4, tc = t & 15;
  float best[4]; int bidx[4];
  #pragma unroll
  for (int i = 0; i < 4; ++i) { best[i] = 3.4e38f; bidx[i] = 0; }
  for (int kt = 0; kt < KCODES; kt += FB_BK) {
    __syncthreads();
    #pragma unroll
    for (int i = 0; i < 8; ++i) {
      int f = t + i * 256; int r = f >> 6, c4 = f & 63;
      *reinterpret_cast<float4*>(&csh[r * FB_LD + c4 * 4]) =
          *reinterpret_cast<const float4*>(cb + (size_t)(kt + r) * DDIM + c4 * 4);
    }
    __syncthreads();
    float acc[4][2] = {{0.f,0.f},{0.f,0.f},{0.f,0.f},{0.f,0.f}};
    #pragma unroll 8
    for (int d4 = 0; d4 < 64; ++d4) {
      float4 b0 = *reinterpret_cast<const float4*>(&csh[tc * FB_LD + d4 * 4]);
      float4 b1v = *reinterpret_cast<const float4*>(&csh[(tc + 16) * FB_LD + d4 * 4]);
      #pragma unroll
      for (int i = 0; i < 4; ++i) {
        float4 a = *reinterpret_cast<const float4*>(&zs[(4 * tr + i) * FB_LD + d4 * 4]);
        acc[i][0] = fmaf(a.x, b0.x, acc[i][0]); acc[i][0] = fmaf(a.y, b0.y, acc[i][0]);
        acc[i][0] = fmaf(a.z, b0.z, acc[i][0]); acc[i][0] = fmaf(a.w, b0.w, acc[i][0]);
        acc[i][1] = fmaf(a.x, b1v.x, acc[i][1]); acc[i][1] = fmaf(a.y, b1v.y, acc[i][1]);
        acc[i][1] = fmaf(a.z, b1v.z, acc[i][1]); acc[i][1] = fmaf(a.w, b1v.w, acc[i][1]);
      }
    }
    float cn0 = cn[kt + tc], cn1 = cn[kt + tc + 16];
    #pragma unroll
    for (int i = 0; i < 4; ++i) {
      float d0 = cn0 - 2.0f * acc[i][0];
      if (d0 < best[i]) { best[i] = d0; bidx[i] = kt + tc; }
      float d1 = cn1 - 2.0f * acc[i][1];
      if (d1 < best[i]) { best[i] = d1; bidx[i] = kt + tc + 16; }
    }
  }
  #pragma unroll
  for (int i = 0; i < 4; ++i) { redd[4 * tr + i][tc] = best[i]; redi[4 * tr + i][tc] = bidx[i]; }
  __syncthreads();
  if (t < FB_BM) {
    float bd = redd[t][0]; int bi = redi[t][0];
    #pragma unroll
    for (int j = 1; j < 16; ++j) {
      float d = redd[t][j]; int ix = redi[t][j];
      if (d < bd || (d == bd && ix < bi)) { bd = d; bi = ix; }
    }
    sidx[t] = bi;
    out[QZ + row0 + t] = (float)bi;
  }
  __syncthreads();
  #pragma unroll
  for (int i = 0; i < 16; ++i) {
    int f = t + i * 256; int r = f >> 6, c4 = f & 63;
    *reinterpret_cast<float4*>(&out[(size_t)(row0 + r) * DDIM + c4 * 4]) =
        *reinterpret_cast<const float4*>(cb + (size_t)sidx[r] * DDIM + c4 * 4);
  }
}

extern "C" void kernel_launch(void* const* d_in, const int* in_sizes, int n_in,
                              void* d_out, int out_size, void* d_ws, size_t ws_size,
                              hipStream_t stream) {
  const float* z  = (const float*)d_in[0];
  const float* cb = (const float*)d_in[1];
  float* out = (float*)d_out;

  const size_t OFF_CN  = (size_t)KCODES * 512;           // 4 MiB wcb
  const size_t OFF_CNT = OFF_CN + (size_t)KCODES * 4;    // cntA @+0, cntB @+4
  const size_t OFF_RA  = OFF_CNT + 16;
  const size_t OFF_RB  = OFF_RA + (size_t)N_ROWS * 16;
  const size_t NEED    = OFF_RB + (size_t)N_ROWS * 4;

  if (ws_size >= NEED) {
    unsigned char* wcb = (unsigned char*)d_ws;
    float* cn = (float*)(wcb + OFF_CN);
    int* cntA = (int*)(wcb + OFF_CNT);
    int* cntB = (int*)(wcb + OFF_CNT + 4);
    int4* rowsA = (int4*)(wcb + OFF_RA);
    int* rowsB = (int*)(wcb + OFF_RB);
    hipMemsetAsync(cntA, 0, 8, stream);
    vq_prep<<<KCODES / 4, 256, 0, stream>>>(cb, wcb, cn);
    vq_mfma<<<N_ROWS / 128, 512, 0, stream>>>(z, wcb, cn, cb, out,
                                              cntA, rowsA, cntB, rowsB);
    vq_pairs<<<128, 256, 0, stream>>>(z, cb, cn, out, cntA, rowsA);
    vq_fullsweep<<<512, 256, 0, stream>>>(z, cb, cn, out, cntB, rowsB);
  } else {
    float* cn = (float*)d_ws;
    vq_cnorm<<<KCODES / 4, 256, 0, stream>>>(cb, cn);
    vq_main_fb<<<N_ROWS / FB_BM, 256, 0, stream>>>(z, cb, cn, out);
  }
}

// Round 6
// 515.561 us; speedup vs baseline: 2.0628x; 2.0151x over previous
//
#include <hip/hip_runtime.h>
#include <hip/hip_bf16.h>

#define N_ROWS 32768
#define DDIM   256
#define KCODES 8192
#define QZ     (N_ROWS * DDIM)
#define NTILES 128            // 8192 codes / 64 per tile
#define MARGIN 0.8f           // ~11 sigma of hi*hi approx-error diff

typedef __attribute__((ext_vector_type(8))) short short8;
typedef __attribute__((ext_vector_type(4))) float f32x4;

__device__ __forceinline__ unsigned short f2bf(float f) {   // RNE float->bf16
  unsigned u = __builtin_bit_cast(unsigned, f);
  u += 0x7FFFu + ((u >> 16) & 1u);
  return (unsigned short)(u >> 16);
}

// insert distance d (code c) into per-row top-3 state (b1<=b2<=b3)
__device__ __forceinline__ void ins(float& b1, float& b2, float& b3, int& i1, int& i2,
                                    float d, int c) {
  bool l3 = d < b3, l2 = d < b2, l1 = d < b1;
  b3 = l3 ? (l2 ? b2 : d) : b3;
  b2 = l2 ? (l1 ? b1 : d) : b2;
  i2 = l2 ? (l1 ? i1 : c) : i2;
  b1 = l1 ? d : b1;
  i1 = l1 ? c : i1;
}

// merge sorted triple (o1<=o2<=o3, idx y1,y2) into (a1<=a2<=a3, idx x1,x2)
__device__ __forceinline__ void merge3(float& a1, float& a2, float& a3, int& x1, int& x2,
                                       float o1, float o2, float o3, int y1, int y2) {
  bool oW = o1 < a1;
  float mx1 = oW ? a1 : o1;  int mxi = oW ? x1 : y1;
  float n1  = oW ? o1 : a1;  int ni1 = oW ? y1 : x1;
  bool lA = a2 < o2;
  float lo2 = lA ? a2 : o2;  int li2 = lA ? x2 : y2;
  float hi2 = lA ? o2 : a2;
  bool m2w = mx1 < lo2;
  float n2 = m2w ? mx1 : lo2; int ni2 = m2w ? mxi : li2;
  float n3 = fminf(fminf(fmaxf(mx1, lo2), hi2), fminf(a3, o3));
  a1 = n1; a2 = n2; a3 = n3; x1 = ni1; x2 = ni2;
}

// ---- cnorm only (fallback path) ----
__global__ __launch_bounds__(256) void vq_cnorm(const float* __restrict__ cb,
                                                float* __restrict__ cn) {
  int n = blockIdx.x * 4 + (threadIdx.x >> 6);
  int lane = threadIdx.x & 63;
  float4 c4 = *reinterpret_cast<const float4*>(cb + (size_t)n * DDIM + lane * 4);
  double s = (double)c4.x * c4.x + (double)c4.y * c4.y +
             (double)c4.z * c4.z + (double)c4.w * c4.w;
  #pragma unroll
  for (int off = 32; off > 0; off >>= 1) s += __shfl_down(s, off, 64);
  if (lane == 0) cn[n] = (float)s;
}

// ---- prep: codebook -> swizzled bf16 HI rows (512B/code) + cnorm ----
__global__ __launch_bounds__(256) void vq_prep(const float* __restrict__ cb,
                                               unsigned char* __restrict__ wcb,
                                               float* __restrict__ cn) {
  int n = blockIdx.x * 4 + (threadIdx.x >> 6);
  int lane = threadIdx.x & 63;
  float4 c4 = *reinterpret_cast<const float4*>(cb + (size_t)n * DDIM + lane * 4);
  double s = (double)c4.x * c4.x + (double)c4.y * c4.y +
             (double)c4.z * c4.z + (double)c4.w * c4.w;
  #pragma unroll
  for (int off = 32; off > 0; off >>= 1) s += __shfl_down(s, off, 64);
  if (lane == 0) cn[n] = (float)s;

  unsigned short h0 = f2bf(c4.x), h1 = f2bf(c4.y), h2 = f2bf(c4.z), h3 = f2bf(c4.w);
  size_t base = (size_t)n * 512 +
                (size_t)((((lane >> 1) ^ (n & 7)) << 4) + (lane & 1) * 8);
  *reinterpret_cast<ushort4*>(wcb + base) = make_ushort4(h0, h1, h2, h3);
}

// ---- main MFMA kernel (unchanged structure from round 5) ----
__global__ __launch_bounds__(512, 1) void vq_mfma(
    const float* __restrict__ z, const unsigned char* __restrict__ wcb,
    const float* __restrict__ cn, const float* __restrict__ cb,
    float* __restrict__ out,
    int* __restrict__ cntA, int4* __restrict__ rowsA,
    int* __restrict__ cntB, int* __restrict__ rowsB) {
  __shared__ __align__(16) unsigned char cs[2][32768];   // 64 codes x 512B, double buffer
  __shared__ float rb1[2][128], rb2[2][128], rb3[2][128];
  __shared__ int   ri1[2][128], ri2[2][128];
  __shared__ int   sIdx[128];

  const int tid = threadIdx.x;
  const int w = tid >> 6, lane = tid & 63;
  const int wm = w >> 1, wn = w & 1;
  const int g = lane >> 4, l15 = lane & 15;

  short8 zh[2][8];
  const int rA = blockIdx.x * 128 + wm * 32 + l15;
  #pragma unroll
  for (int mf = 0; mf < 2; ++mf) {
    #pragma unroll
    for (int dc = 0; dc < 8; ++dc) {
      const float* zp = z + (size_t)(rA + mf * 16) * DDIM + dc * 32 + g * 8;
      float4 f0 = *reinterpret_cast<const float4*>(zp);
      float4 f1 = *reinterpret_cast<const float4*>(zp + 4);
      short8 hh;
      hh[0] = (short)f2bf(f0.x); hh[1] = (short)f2bf(f0.y);
      hh[2] = (short)f2bf(f0.z); hh[3] = (short)f2bf(f0.w);
      hh[4] = (short)f2bf(f1.x); hh[5] = (short)f2bf(f1.y);
      hh[6] = (short)f2bf(f1.z); hh[7] = (short)f2bf(f1.w);
      zh[mf][dc] = hh;
    }
  }

  float b1[8], b2[8], b3[8];
  int i1[8], i2[8];
  #pragma unroll
  for (int s = 0; s < 8; ++s) { b1[s] = 3.4e38f; b2[s] = 3.4e38f; b3[s] = 3.4e38f; i1[s] = 0; i2[s] = 0; }

  #pragma unroll
  for (int i = 0; i < 4; ++i) {
    __builtin_amdgcn_global_load_lds(
        (const __attribute__((address_space(1))) void*)(wcb + tid * 16 + i * 8192),
        (__attribute__((address_space(3))) void*)(&cs[0][tid * 16 + i * 8192]), 16, 0, 0);
  }
  __syncthreads();

  const int cc0 = wn * 32 + l15;
  const int cc1 = cc0 + 16;
  const int swz = cc0 & 7;

  for (int nt = 0; nt < NTILES; ++nt) {
    const int cur = nt & 1;
    if (nt + 1 < NTILES) {
      const unsigned char* gsrc = wcb + (size_t)(nt + 1) * 32768;
      #pragma unroll
      for (int i = 0; i < 4; ++i) {
        __builtin_amdgcn_global_load_lds(
            (const __attribute__((address_space(1))) void*)(gsrc + tid * 16 + i * 8192),
            (__attribute__((address_space(3))) void*)(&cs[cur ^ 1][tid * 16 + i * 8192]), 16, 0, 0);
      }
    }

    int code0 = nt * 64 + cc0;
    float cn0 = cn[code0];
    float cn1 = cn[code0 + 16];

    const unsigned char* lb = cs[cur];
    f32x4 a00 = {0.f, 0.f, 0.f, 0.f}, a01 = a00, a10 = a00, a11 = a00;
    #pragma unroll
    for (int dc = 0; dc < 8; ++dc) {
      int u = dc * 4 + g;
      int o0 = cc0 * 512 + ((u ^ swz) << 4);
      int o1 = cc1 * 512 + ((u ^ swz) << 4);
      short8 c0 = *reinterpret_cast<const short8*>(lb + o0);
      short8 c1 = *reinterpret_cast<const short8*>(lb + o1);
      a00 = __builtin_amdgcn_mfma_f32_16x16x32_bf16(zh[0][dc], c0, a00, 0, 0, 0);
      a01 = __builtin_amdgcn_mfma_f32_16x16x32_bf16(zh[0][dc], c1, a01, 0, 0, 0);
      a10 = __builtin_amdgcn_mfma_f32_16x16x32_bf16(zh[1][dc], c0, a10, 0, 0, 0);
      a11 = __builtin_amdgcn_mfma_f32_16x16x32_bf16(zh[1][dc], c1, a11, 0, 0, 0);
    }

    #pragma unroll
    for (int mf = 0; mf < 2; ++mf) {
      const f32x4 an0 = mf ? a10 : a00;
      const f32x4 an1 = mf ? a11 : a01;
      #pragma unroll
      for (int r = 0; r < 4; ++r) {
        const int s = mf * 4 + r;
        float d0 = fmaf(-2.0f, an0[r], cn0);
        ins(b1[s], b2[s], b3[s], i1[s], i2[s], d0, code0);
        float d1 = fmaf(-2.0f, an1[r], cn1);
        ins(b1[s], b2[s], b3[s], i1[s], i2[s], d1, code0 + 16);
      }
    }
    __syncthreads();
  }

  #pragma unroll
  for (int s = 0; s < 8; ++s) {
    float B1 = b1[s], B2 = b2[s], B3 = b3[s];
    int I1 = i1[s], I2 = i2[s];
    #pragma unroll
    for (int m = 1; m <= 8; m <<= 1) {
      float o1 = __shfl_xor(B1, m, 64), o2 = __shfl_xor(B2, m, 64), o3 = __shfl_xor(B3, m, 64);
      int y1 = __shfl_xor(I1, m, 64), y2 = __shfl_xor(I2, m, 64);
      merge3(B1, B2, B3, I1, I2, o1, o2, o3, y1, y2);
    }
    if (l15 == 0) {
      int row = wm * 32 + (s >> 2) * 16 + g * 4 + (s & 3);
      rb1[wn][row] = B1; rb2[wn][row] = B2; rb3[wn][row] = B3;
      ri1[wn][row] = I1; ri2[wn][row] = I2;
    }
  }
  __syncthreads();

  if (tid < 128) {
    float B1 = rb1[0][tid], B2 = rb2[0][tid], B3 = rb3[0][tid];
    int I1 = ri1[0][tid], I2 = ri2[0][tid];
    merge3(B1, B2, B3, I1, I2, rb1[1][tid], rb2[1][tid], rb3[1][tid], ri1[1][tid], ri2[1][tid]);
    int grow = blockIdx.x * 128 + tid;
    out[QZ + grow] = (float)I1;
    sIdx[tid] = I1;
    if (B3 - B1 < MARGIN) {
      int p = atomicAdd(cntB, 1);
      rowsB[p] = grow;
    } else if (B2 - B1 < MARGIN) {
      int p = atomicAdd(cntA, 1);
      rowsA[p] = make_int4(grow, I1, I2, 0);
    }
  }
  __syncthreads();

  #pragma unroll
  for (int i = 0; i < 16; ++i) {
    int f = tid + i * 512;
    int r = f >> 6, c4i = f & 63;
    float4 v = *reinterpret_cast<const float4*>(cb + (size_t)sIdx[r] * DDIM + c4i * 4);
    *reinterpret_cast<float4*>(&out[(size_t)(blockIdx.x * 128 + r) * DDIM + c4i * 4]) = v;
  }
}

// ---- cleanup A: exact fp32 compare of top-2 candidates per flagged row ----
__global__ __launch_bounds__(256) void vq_pairs(
    const float* __restrict__ z, const float* __restrict__ cb, const float* __restrict__ cn,
    float* __restrict__ out, const int* __restrict__ cntA, const int4* __restrict__ rowsA) {
  int n = *cntA;
  int lane = threadIdx.x & 63;
  for (int e = blockIdx.x * 4 + (threadIdx.x >> 6); e < n; e += gridDim.x * 4) {
    int4 ent = rowsA[e];
    int row = ent.x, c1 = ent.y, c2 = ent.z;
    float4 zv = *reinterpret_cast<const float4*>(z + (size_t)row * DDIM + lane * 4);
    float4 a = *reinterpret_cast<const float4*>(cb + (size_t)c1 * DDIM + lane * 4);
    float4 b = *reinterpret_cast<const float4*>(cb + (size_t)c2 * DDIM + lane * 4);
    float p1 = zv.x * a.x + zv.y * a.y + zv.z * a.z + zv.w * a.w;
    float p2 = zv.x * b.x + zv.y * b.y + zv.z * b.z + zv.w * b.w;
    #pragma unroll
    for (int m = 1; m <= 32; m <<= 1) { p1 += __shfl_xor(p1, m, 64); p2 += __shfl_xor(p2, m, 64); }
    float d1 = cn[c1] - 2.0f * p1;
    float d2 = cn[c2] - 2.0f * p2;
    int win = (d2 < d1 || (d2 == d1 && c2 < c1)) ? c2 : c1;
    if (lane == 0) out[QZ + row] = (float)win;
    float4 cw = *reinterpret_cast<const float4*>(cb + (size_t)win * DDIM + lane * 4);
    *reinterpret_cast<float4*>(&out[(size_t)row * DDIM + lane * 4]) = cw;
  }
}

// ---- cleanup B: exact fp32 full-codebook argmin, LDS-staged chunk x row-loop ----
// 64 chunk-blocks x 4 row-splits. Block stages 128 codes into padded LDS once
// (coalesced), then per flagged row: stage z-row (1KB), each thread computes a
// 64-dim quarter-dot of 2 codes (z reads broadcast, code reads 2-way-free),
// LDS part[] combine, 64-lane key-min, one u64 atomicMin per wave. No per-code
// shuffles -> O(nB*K*D) MACs at near-VALU rate.
#define FS_CODES 128
#define FS_PAD   257
__global__ __launch_bounds__(256) void vq_fullsweep(
    const float* __restrict__ z, const float* __restrict__ cb, const float* __restrict__ cn,
    const int* __restrict__ cntB, const int* __restrict__ rowsB,
    unsigned long long* __restrict__ keysB) {
  __shared__ float csL[FS_CODES * FS_PAD];   // ~131.6 KB
  __shared__ float zr[DDIM];
  __shared__ float part[4][FS_CODES];
  const int nB = *cntB;
  if (nB == 0) return;
  const int cid = blockIdx.x & 63;           // code chunk
  const int sid = blockIdx.x >> 6;           // row split (0..3)
  const int t = threadIdx.x;
  const int q = t >> 6, k = t & 63;

  // stage 128 codes (32 KB) coalesced into padded LDS
  const float* src = cb + (size_t)cid * FS_CODES * DDIM;
  #pragma unroll
  for (int i = 0; i < 32; ++i) {
    int f = t + i * 256;                     // float4 index
    int code = f >> 6, j = f & 63;
    float4 v = *reinterpret_cast<const float4*>(src + (size_t)f * 4);
    *reinterpret_cast<float4*>(&csL[code * FS_PAD + j * 4]) = v;
  }
  float cnk = (t < FS_CODES) ? cn[cid * FS_CODES + t] : 0.f;

  for (int r = sid; r < nB; r += 4) {
    const int row = rowsB[r];
    __syncthreads();                         // prev row's part reads done
    if (t < 64)
      *reinterpret_cast<float4*>(&zr[t * 4]) =
          *reinterpret_cast<const float4*>(z + (size_t)row * DDIM + t * 4);
    __syncthreads();

    float acc0 = 0.f, acc1 = 0.f;
    #pragma unroll
    for (int j = 0; j < 16; ++j) {
      float4 a  = *reinterpret_cast<const float4*>(&zr[q * 64 + j * 4]);      // broadcast
      float4 c0 = *reinterpret_cast<const float4*>(&csL[k * FS_PAD + q * 64 + j * 4]);
      float4 c1 = *reinterpret_cast<const float4*>(&csL[(k + 64) * FS_PAD + q * 64 + j * 4]);
      acc0 = fmaf(a.x, c0.x, acc0); acc0 = fmaf(a.y, c0.y, acc0);
      acc0 = fmaf(a.z, c0.z, acc0); acc0 = fmaf(a.w, c0.w, acc0);
      acc1 = fmaf(a.x, c1.x, acc1); acc1 = fmaf(a.y, c1.y, acc1);
      acc1 = fmaf(a.z, c1.z, acc1); acc1 = fmaf(a.w, c1.w, acc1);
    }
    part[q][k] = acc0;
    part[q][k + 64] = acc1;
    __syncthreads();

    if (t < FS_CODES) {
      float dot = part[0][t] + part[1][t] + part[2][t] + part[3][t];
      float d = cnk - 2.0f * dot;
      int code = cid * FS_CODES + t;
      unsigned m = __builtin_bit_cast(unsigned, d);
      m = (m >> 31) ? ~m : (m | 0x80000000u);
      unsigned long long key = ((unsigned long long)m << 32) | (unsigned)code;
      #pragma unroll
      for (int mm = 1; mm <= 32; mm <<= 1) {
        unsigned long long o = __shfl_xor(key, mm, 64);
        key = (o < key) ? o : key;
      }
      if (k == 0) atomicMin(&keysB[r], key);
    }
  }
}

// ---- finish B: write index + gather for full-swept rows ----
__global__ __launch_bounds__(256) void vq_finishB(
    const float* __restrict__ cb, float* __restrict__ out,
    const int* __restrict__ cntB, const int* __restrict__ rowsB,
    const unsigned long long* __restrict__ keysB) {
  int nB = *cntB;
  int lane = threadIdx.x & 63;
  for (int e = blockIdx.x * 4 + (threadIdx.x >> 6); e < nB; e += gridDim.x * 4) {
    int row = rowsB[e];
    int idx = (int)(keysB[e] & 0xFFFFFFFFULL);
    if (lane == 0) out[QZ + row] = (float)idx;
    *reinterpret_cast<float4*>(&out[(size_t)row * DDIM + lane * 4]) =
        *reinterpret_cast<const float4*>(cb + (size_t)idx * DDIM + lane * 4);
  }
}

// ---- round-1 fp32 fallback (only if ws too small) ----
#define FB_BM 64
#define FB_BK 32
#define FB_LD 260
__global__ __launch_bounds__(256) void vq_main_fb(const float* __restrict__ z,
                                                  const float* __restrict__ cb,
                                                  const float* __restrict__ cn,
                                                  float* __restrict__ out) {
  __shared__ float zs[FB_BM * FB_LD];
  __shared__ float csh[FB_BK * FB_LD];
  __shared__ float redd[FB_BM][16];
  __shared__ int   redi[FB_BM][16];
  __shared__ int   sidx[FB_BM];
  const int t = threadIdx.x;
  const int row0 = blockIdx.x * FB_BM;
  #pragma unroll
  for (int i = 0; i < 16; ++i) {
    int f = t + i * 256; int r = f >> 6, c4 = f & 63;
    *reinterpret_cast<float4*>(&zs[r * FB_LD + c4 * 4]) =
        *reinterpret_cast<const float4*>(z + (size_t)(row0 + r) * DDIM + c4 * 4);
  }
  const int tr = t >> 4, tc = t & 15;
  float best[4]; int bidx[4];
  #pragma unroll
  for (int i = 0; i < 4; ++i) { best[i] = 3.4e38f; bidx[i] = 0; }
  for (int kt = 0; kt < KCODES; kt += FB_BK) {
    __syncthreads();
    #pragma unroll
    for (int i = 0; i < 8; ++i) {
      int f = t + i * 256; int r = f >> 6, c4 = f & 63;
      *reinterpret_cast<float4*>(&csh[r * FB_LD + c4 * 4]) =
          *reinterpret_cast<const float4*>(cb + (size_t)(kt + r) * DDIM + c4 * 4);
    }
    __syncthreads();
    float acc[4][2] = {{0.f,0.f},{0.f,0.f},{0.f,0.f},{0.f,0.f}};
    #pragma unroll 8
    for (int d4 = 0; d4 < 64; ++d4) {
      float4 b0 = *reinterpret_cast<const float4*>(&csh[tc * FB_LD + d4 * 4]);
      float4 b1v = *reinterpret_cast<const float4*>(&csh[(tc + 16) * FB_LD + d4 * 4]);
      #pragma unroll
      for (int i = 0; i < 4; ++i) {
        float4 a = *reinterpret_cast<const float4*>(&zs[(4 * tr + i) * FB_LD + d4 * 4]);
        acc[i][0] = fmaf(a.x, b0.x, acc[i][0]); acc[i][0] = fmaf(a.y, b0.y, acc[i][0]);
        acc[i][0] = fmaf(a.z, b0.z, acc[i][0]); acc[i][0] = fmaf(a.w, b0.w, acc[i][0]);
        acc[i][1] = fmaf(a.x, b1v.x, acc[i][1]); acc[i][1] = fmaf(a.y, b1v.y, acc[i][1]);
        acc[i][1] = fmaf(a.z, b1v.z, acc[i][1]); acc[i][1] = fmaf(a.w, b1v.w, acc[i][1]);
      }
    }
    float cn0 = cn[kt + tc], cn1 = cn[kt + tc + 16];
    #pragma unroll
    for (int i = 0; i < 4; ++i) {
      float d0 = cn0 - 2.0f * acc[i][0];
      if (d0 < best[i]) { best[i] = d0; bidx[i] = kt + tc; }
      float d1 = cn1 - 2.0f * acc[i][1];
      if (d1 < best[i]) { best[i] = d1; bidx[i] = kt + tc + 16; }
    }
  }
  #pragma unroll
  for (int i = 0; i < 4; ++i) { redd[4 * tr + i][tc] = best[i]; redi[4 * tr + i][tc] = bidx[i]; }
  __syncthreads();
  if (t < FB_BM) {
    float bd = redd[t][0]; int bi = redi[t][0];
    #pragma unroll
    for (int j = 1; j < 16; ++j) {
      float d = redd[t][j]; int ix = redi[t][j];
      if (d < bd || (d == bd && ix < bi)) { bd = d; bi = ix; }
    }
    sidx[t] = bi;
    out[QZ + row0 + t] = (float)bi;
  }
  __syncthreads();
  #pragma unroll
  for (int i = 0; i < 16; ++i) {
    int f = t + i * 256; int r = f >> 6, c4 = f & 63;
    *reinterpret_cast<float4*>(&out[(size_t)(row0 + r) * DDIM + c4 * 4]) =
        *reinterpret_cast<const float4*>(cb + (size_t)sidx[r] * DDIM + c4 * 4);
  }
}

extern "C" void kernel_launch(void* const* d_in, const int* in_sizes, int n_in,
                              void* d_out, int out_size, void* d_ws, size_t ws_size,
                              hipStream_t stream) {
  const float* z  = (const float*)d_in[0];
  const float* cb = (const float*)d_in[1];
  float* out = (float*)d_out;

  const size_t OFF_CN   = (size_t)KCODES * 512;            // 4 MiB wcb
  const size_t OFF_CNT  = OFF_CN + (size_t)KCODES * 4;
  const size_t OFF_RA   = OFF_CNT + 16;
  const size_t OFF_RB   = OFF_RA + (size_t)N_ROWS * 16;
  const size_t OFF_KEYS = OFF_RB + (size_t)N_ROWS * 4;
  const size_t NEED     = OFF_KEYS + (size_t)N_ROWS * 8;

  if (ws_size >= NEED) {
    unsigned char* wcb = (unsigned char*)d_ws;
    float* cn = (float*)(wcb + OFF_CN);
    int* cntA = (int*)(wcb + OFF_CNT);
    int* cntB = (int*)(wcb + OFF_CNT + 4);
    int4* rowsA = (int4*)(wcb + OFF_RA);
    int* rowsB = (int*)(wcb + OFF_RB);
    unsigned long long* keysB = (unsigned long long*)(wcb + OFF_KEYS);
    hipMemsetAsync(cntA, 0, 8, stream);
    hipMemsetAsync(keysB, 0xFF, (size_t)N_ROWS * 8, stream);
    vq_prep<<<KCODES / 4, 256, 0, stream>>>(cb, wcb, cn);
    vq_mfma<<<N_ROWS / 128, 512, 0, stream>>>(z, wcb, cn, cb, out,
                                              cntA, rowsA, cntB, rowsB);
    vq_pairs<<<128, 256, 0, stream>>>(z, cb, cn, out, cntA, rowsA);
    vq_fullsweep<<<256, 256, 0, stream>>>(z, cb, cn, cntB, rowsB, keysB);
    vq_finishB<<<64, 256, 0, stream>>>(cb, out, cntB, rowsB, keysB);
  } else {
    float* cn = (float*)d_ws;
    vq_cnorm<<<KCODES / 4, 256, 0, stream>>>(cb, cn);
    vq_main_fb<<<N_ROWS / FB_BM, 256, 0, stream>>>(z, cb, cn, out);
  }
}

// Round 7
// 476.280 us; speedup vs baseline: 2.2329x; 1.0825x over previous
//
#include <hip/hip_runtime.h>
#include <hip/hip_bf16.h>

#define N_ROWS 32768
#define DDIM   256
#define KCODES 8192
#define QZ     (N_ROWS * DDIM)
#define NTILES 128            // 8192 codes / 64 per tile
#define MARGIN 0.8f           // ~6 sigma of hi*hi approx-error diff (passed 2x at this)

typedef __attribute__((ext_vector_type(8))) short short8;
typedef __attribute__((ext_vector_type(4))) float f32x4;

__device__ __forceinline__ unsigned short f2bf(float f) {   // RNE float->bf16
  unsigned u = __builtin_bit_cast(unsigned, f);
  u += 0x7FFFu + ((u >> 16) & 1u);
  return (unsigned short)(u >> 16);
}

// insert distance d (code c) into per-row top-3 state (b1<=b2<=b3)
__device__ __forceinline__ void ins(float& b1, float& b2, float& b3, int& i1, int& i2,
                                    float d, int c) {
  bool l3 = d < b3, l2 = d < b2, l1 = d < b1;
  b3 = l3 ? (l2 ? b2 : d) : b3;
  b2 = l2 ? (l1 ? b1 : d) : b2;
  i2 = l2 ? (l1 ? i1 : c) : i2;
  b1 = l1 ? d : b1;
  i1 = l1 ? c : i1;
}

// merge sorted triple (o1<=o2<=o3, idx y1,y2) into (a1<=a2<=a3, idx x1,x2)
__device__ __forceinline__ void merge3(float& a1, float& a2, float& a3, int& x1, int& x2,
                                       float o1, float o2, float o3, int y1, int y2) {
  bool oW = o1 < a1;
  float mx1 = oW ? a1 : o1;  int mxi = oW ? x1 : y1;
  float n1  = oW ? o1 : a1;  int ni1 = oW ? y1 : x1;
  bool lA = a2 < o2;
  float lo2 = lA ? a2 : o2;  int li2 = lA ? x2 : y2;
  float hi2 = lA ? o2 : a2;
  bool m2w = mx1 < lo2;
  float n2 = m2w ? mx1 : lo2; int ni2 = m2w ? mxi : li2;
  float n3 = fminf(fminf(fmaxf(mx1, lo2), hi2), fminf(a3, o3));
  a1 = n1; a2 = n2; a3 = n3; x1 = ni1; x2 = ni2;
}

// ---- cnorm only (fallback path) ----
__global__ __launch_bounds__(256) void vq_cnorm(const float* __restrict__ cb,
                                                float* __restrict__ cn) {
  int n = blockIdx.x * 4 + (threadIdx.x >> 6);
  int lane = threadIdx.x & 63;
  float4 c4 = *reinterpret_cast<const float4*>(cb + (size_t)n * DDIM + lane * 4);
  double s = (double)c4.x * c4.x + (double)c4.y * c4.y +
             (double)c4.z * c4.z + (double)c4.w * c4.w;
  #pragma unroll
  for (int off = 32; off > 0; off >>= 1) s += __shfl_down(s, off, 64);
  if (lane == 0) cn[n] = (float)s;
}

// ---- prep: codebook -> swizzled bf16 HI rows (512B/code) + cnorm ----
__global__ __launch_bounds__(256) void vq_prep(const float* __restrict__ cb,
                                               unsigned char* __restrict__ wcb,
                                               float* __restrict__ cn) {
  int n = blockIdx.x * 4 + (threadIdx.x >> 6);
  int lane = threadIdx.x & 63;
  float4 c4 = *reinterpret_cast<const float4*>(cb + (size_t)n * DDIM + lane * 4);
  double s = (double)c4.x * c4.x + (double)c4.y * c4.y +
             (double)c4.z * c4.z + (double)c4.w * c4.w;
  #pragma unroll
  for (int off = 32; off > 0; off >>= 1) s += __shfl_down(s, off, 64);
  if (lane == 0) cn[n] = (float)s;

  unsigned short h0 = f2bf(c4.x), h1 = f2bf(c4.y), h2 = f2bf(c4.z), h3 = f2bf(c4.w);
  size_t base = (size_t)n * 512 +
                (size_t)((((lane >> 1) ^ (n & 7)) << 4) + (lane & 1) * 8);
  *reinterpret_cast<ushort4*>(wcb + base) = make_ushort4(h0, h1, h2, h3);
}

// ---- main MFMA kernel: 512 blocks x 256 thr (4 waves); block = 64 rows x full K ----
// 2 blocks/CU -> independent barrier domains overlap (stall hiding).
// waves: 2 wm x 2 wn; wave tile = 32 rows (2 mfrags) x 32 codes (2 nfrags); A = hi bf16
__global__ __launch_bounds__(256, 2) void vq_mfma(
    const float* __restrict__ z, const unsigned char* __restrict__ wcb,
    const float* __restrict__ cn, const float* __restrict__ cb,
    float* __restrict__ out,
    int* __restrict__ cntA, int4* __restrict__ rowsA,
    int* __restrict__ cntB, int* __restrict__ rowsB) {
  __shared__ __align__(16) unsigned char cs[2][32768];   // 64 codes x 512B, double buffer
  __shared__ float rb1[2][64], rb2[2][64], rb3[2][64];
  __shared__ int   ri1[2][64], ri2[2][64];
  __shared__ int   sIdx[64];

  const int tid = threadIdx.x;
  const int w = tid >> 6, lane = tid & 63;
  const int wm = w >> 1, wn = w & 1;
  const int g = lane >> 4, l15 = lane & 15;

  short8 zh[2][8];
  const int rA = blockIdx.x * 64 + wm * 32 + l15;
  #pragma unroll
  for (int mf = 0; mf < 2; ++mf) {
    #pragma unroll
    for (int dc = 0; dc < 8; ++dc) {
      const float* zp = z + (size_t)(rA + mf * 16) * DDIM + dc * 32 + g * 8;
      float4 f0 = *reinterpret_cast<const float4*>(zp);
      float4 f1 = *reinterpret_cast<const float4*>(zp + 4);
      short8 hh;
      hh[0] = (short)f2bf(f0.x); hh[1] = (short)f2bf(f0.y);
      hh[2] = (short)f2bf(f0.z); hh[3] = (short)f2bf(f0.w);
      hh[4] = (short)f2bf(f1.x); hh[5] = (short)f2bf(f1.y);
      hh[6] = (short)f2bf(f1.z); hh[7] = (short)f2bf(f1.w);
      zh[mf][dc] = hh;
    }
  }

  float b1[8], b2[8], b3[8];
  int i1[8], i2[8];
  #pragma unroll
  for (int s = 0; s < 8; ++s) { b1[s] = 3.4e38f; b2[s] = 3.4e38f; b3[s] = 3.4e38f; i1[s] = 0; i2[s] = 0; }

  // stage tile 0 (32KB: 256 thr x 8 x 16B, wave-linear dest, pre-swizzled src)
  #pragma unroll
  for (int i = 0; i < 8; ++i) {
    __builtin_amdgcn_global_load_lds(
        (const __attribute__((address_space(1))) void*)(wcb + tid * 16 + i * 4096),
        (__attribute__((address_space(3))) void*)(&cs[0][tid * 16 + i * 4096]), 16, 0, 0);
  }
  __syncthreads();

  const int cc0 = wn * 32 + l15;
  const int cc1 = cc0 + 16;
  const int swz = cc0 & 7;

  for (int nt = 0; nt < NTILES; ++nt) {
    const int cur = nt & 1;
    if (nt + 1 < NTILES) {
      const unsigned char* gsrc = wcb + (size_t)(nt + 1) * 32768;
      #pragma unroll
      for (int i = 0; i < 8; ++i) {
        __builtin_amdgcn_global_load_lds(
            (const __attribute__((address_space(1))) void*)(gsrc + tid * 16 + i * 4096),
            (__attribute__((address_space(3))) void*)(&cs[cur ^ 1][tid * 16 + i * 4096]), 16, 0, 0);
      }
    }

    int code0 = nt * 64 + cc0;
    float cn0 = cn[code0];
    float cn1 = cn[code0 + 16];

    const unsigned char* lb = cs[cur];
    f32x4 a00 = {0.f, 0.f, 0.f, 0.f}, a01 = a00, a10 = a00, a11 = a00;
    #pragma unroll
    for (int dc = 0; dc < 8; ++dc) {
      int u = dc * 4 + g;
      int o0 = cc0 * 512 + ((u ^ swz) << 4);
      int o1 = cc1 * 512 + ((u ^ swz) << 4);
      short8 c0 = *reinterpret_cast<const short8*>(lb + o0);
      short8 c1 = *reinterpret_cast<const short8*>(lb + o1);
      a00 = __builtin_amdgcn_mfma_f32_16x16x32_bf16(zh[0][dc], c0, a00, 0, 0, 0);
      a01 = __builtin_amdgcn_mfma_f32_16x16x32_bf16(zh[0][dc], c1, a01, 0, 0, 0);
      a10 = __builtin_amdgcn_mfma_f32_16x16x32_bf16(zh[1][dc], c0, a10, 0, 0, 0);
      a11 = __builtin_amdgcn_mfma_f32_16x16x32_bf16(zh[1][dc], c1, a11, 0, 0, 0);
    }

    #pragma unroll
    for (int mf = 0; mf < 2; ++mf) {
      const f32x4 an0 = mf ? a10 : a00;
      const f32x4 an1 = mf ? a11 : a01;
      #pragma unroll
      for (int r = 0; r < 4; ++r) {
        const int s = mf * 4 + r;
        float d0 = fmaf(-2.0f, an0[r], cn0);
        ins(b1[s], b2[s], b3[s], i1[s], i2[s], d0, code0);
        float d1 = fmaf(-2.0f, an1[r], cn1);
        ins(b1[s], b2[s], b3[s], i1[s], i2[s], d1, code0 + 16);
      }
    }
    __syncthreads();
  }

  #pragma unroll
  for (int s = 0; s < 8; ++s) {
    float B1 = b1[s], B2 = b2[s], B3 = b3[s];
    int I1 = i1[s], I2 = i2[s];
    #pragma unroll
    for (int m = 1; m <= 8; m <<= 1) {
      float o1 = __shfl_xor(B1, m, 64), o2 = __shfl_xor(B2, m, 64), o3 = __shfl_xor(B3, m, 64);
      int y1 = __shfl_xor(I1, m, 64), y2 = __shfl_xor(I2, m, 64);
      merge3(B1, B2, B3, I1, I2, o1, o2, o3, y1, y2);
    }
    if (l15 == 0) {
      int row = wm * 32 + (s >> 2) * 16 + g * 4 + (s & 3);
      rb1[wn][row] = B1; rb2[wn][row] = B2; rb3[wn][row] = B3;
      ri1[wn][row] = I1; ri2[wn][row] = I2;
    }
  }
  __syncthreads();

  if (tid < 64) {
    float B1 = rb1[0][tid], B2 = rb2[0][tid], B3 = rb3[0][tid];
    int I1 = ri1[0][tid], I2 = ri2[0][tid];
    merge3(B1, B2, B3, I1, I2, rb1[1][tid], rb2[1][tid], rb3[1][tid], ri1[1][tid], ri2[1][tid]);
    int grow = blockIdx.x * 64 + tid;
    out[QZ + grow] = (float)I1;
    sIdx[tid] = I1;
    if (B3 - B1 < MARGIN) {
      int p = atomicAdd(cntB, 1);
      rowsB[p] = grow;
    } else if (B2 - B1 < MARGIN) {
      int p = atomicAdd(cntA, 1);
      rowsA[p] = make_int4(grow, I1, I2, 0);
    }
  }
  __syncthreads();

  // gather q_z = codebook[idx]: 64 rows x 64 float4
  #pragma unroll
  for (int i = 0; i < 16; ++i) {
    int f = tid + i * 256;
    int r = f >> 6, c4i = f & 63;
    float4 v = *reinterpret_cast<const float4*>(cb + (size_t)sIdx[r] * DDIM + c4i * 4);
    *reinterpret_cast<float4*>(&out[(size_t)(blockIdx.x * 64 + r) * DDIM + c4i * 4]) = v;
  }
}

// ---- cleanup A: exact fp32 compare of top-2 candidates per flagged row ----
__global__ __launch_bounds__(256) void vq_pairs(
    const float* __restrict__ z, const float* __restrict__ cb, const float* __restrict__ cn,
    float* __restrict__ out, const int* __restrict__ cntA, const int4* __restrict__ rowsA) {
  int n = *cntA;
  int lane = threadIdx.x & 63;
  for (int e = blockIdx.x * 4 + (threadIdx.x >> 6); e < n; e += gridDim.x * 4) {
    int4 ent = rowsA[e];
    int row = ent.x, c1 = ent.y, c2 = ent.z;
    float4 zv = *reinterpret_cast<const float4*>(z + (size_t)row * DDIM + lane * 4);
    float4 a = *reinterpret_cast<const float4*>(cb + (size_t)c1 * DDIM + lane * 4);
    float4 b = *reinterpret_cast<const float4*>(cb + (size_t)c2 * DDIM + lane * 4);
    float p1 = zv.x * a.x + zv.y * a.y + zv.z * a.z + zv.w * a.w;
    float p2 = zv.x * b.x + zv.y * b.y + zv.z * b.z + zv.w * b.w;
    #pragma unroll
    for (int m = 1; m <= 32; m <<= 1) { p1 += __shfl_xor(p1, m, 64); p2 += __shfl_xor(p2, m, 64); }
    float d1 = cn[c1] - 2.0f * p1;
    float d2 = cn[c2] - 2.0f * p2;
    int win = (d2 < d1 || (d2 == d1 && c2 < c1)) ? c2 : c1;
    if (lane == 0) out[QZ + row] = (float)win;
    float4 cw = *reinterpret_cast<const float4*>(cb + (size_t)win * DDIM + lane * 4);
    *reinterpret_cast<float4*>(&out[(size_t)row * DDIM + lane * 4]) = cw;
  }
}

// ---- cleanup B: exact fp32 full-codebook argmin, LDS-staged chunk x row-loop ----
#define FS_CODES 128
#define FS_PAD   257
__global__ __launch_bounds__(256) void vq_fullsweep(
    const float* __restrict__ z, const float* __restrict__ cb, const float* __restrict__ cn,
    const int* __restrict__ cntB, const int* __restrict__ rowsB,
    unsigned long long* __restrict__ keysB) {
  __shared__ float csL[FS_CODES * FS_PAD];   // ~131.6 KB
  __shared__ float zr[DDIM];
  __shared__ float part[4][FS_CODES];
  const int nB = *cntB;
  if (nB == 0) return;
  const int cid = blockIdx.x & 63;           // code chunk
  const int sid = blockIdx.x >> 6;           // row split (0..3)
  const int t = threadIdx.x;
  const int q = t >> 6, k = t & 63;

  const float* src = cb + (size_t)cid * FS_CODES * DDIM;
  #pragma unroll
  for (int i = 0; i < 32; ++i) {
    int f = t + i * 256;
    int code = f >> 6, j = f & 63;
    float4 v = *reinterpret_cast<const float4*>(src + (size_t)f * 4);
    *reinterpret_cast<float4*>(&csL[code * FS_PAD + j * 4]) = v;
  }
  float cnk = (t < FS_CODES) ? cn[cid * FS_CODES + t] : 0.f;

  for (int r = sid; r < nB; r += 4) {
    const int row = rowsB[r];
    __syncthreads();
    if (t < 64)
      *reinterpret_cast<float4*>(&zr[t * 4]) =
          *reinterpret_cast<const float4*>(z + (size_t)row * DDIM + t * 4);
    __syncthreads();

    float acc0 = 0.f, acc1 = 0.f;
    #pragma unroll
    for (int j = 0; j < 16; ++j) {
      float4 a  = *reinterpret_cast<const float4*>(&zr[q * 64 + j * 4]);
      float4 c0 = *reinterpret_cast<const float4*>(&csL[k * FS_PAD + q * 64 + j * 4]);
      float4 c1 = *reinterpret_cast<const float4*>(&csL[(k + 64) * FS_PAD + q * 64 + j * 4]);
      acc0 = fmaf(a.x, c0.x, acc0); acc0 = fmaf(a.y, c0.y, acc0);
      acc0 = fmaf(a.z, c0.z, acc0); acc0 = fmaf(a.w, c0.w, acc0);
      acc1 = fmaf(a.x, c1.x, acc1); acc1 = fmaf(a.y, c1.y, acc1);
      acc1 = fmaf(a.z, c1.z, acc1); acc1 = fmaf(a.w, c1.w, acc1);
    }
    part[q][k] = acc0;
    part[q][k + 64] = acc1;
    __syncthreads();

    if (t < FS_CODES) {
      float dot = part[0][t] + part[1][t] + part[2][t] + part[3][t];
      float d = cnk - 2.0f * dot;
      int code = cid * FS_CODES + t;
      unsigned m = __builtin_bit_cast(unsigned, d);
      m = (m >> 31) ? ~m : (m | 0x80000000u);
      unsigned long long key = ((unsigned long long)m << 32) | (unsigned)code;
      #pragma unroll
      for (int mm = 1; mm <= 32; mm <<= 1) {
        unsigned long long o = __shfl_xor(key, mm, 64);
        key = (o < key) ? o : key;
      }
      if (k == 0) atomicMin(&keysB[r], key);
    }
  }
}

// ---- finish B: write index + gather for full-swept rows ----
__global__ __launch_bounds__(256) void vq_finishB(
    const float* __restrict__ cb, float* __restrict__ out,
    const int* __restrict__ cntB, const int* __restrict__ rowsB,
    const unsigned long long* __restrict__ keysB) {
  int nB = *cntB;
  int lane = threadIdx.x & 63;
  for (int e = blockIdx.x * 4 + (threadIdx.x >> 6); e < nB; e += gridDim.x * 4) {
    int row = rowsB[e];
    int idx = (int)(keysB[e] & 0xFFFFFFFFULL);
    if (lane == 0) out[QZ + row] = (float)idx;
    *reinterpret_cast<float4*>(&out[(size_t)row * DDIM + lane * 4]) =
        *reinterpret_cast<const float4*>(cb + (size_t)idx * DDIM + lane * 4);
  }
}

// ---- round-1 fp32 fallback (only if ws too small) ----
#define FB_BM 64
#define FB_BK 32
#define FB_LD 260
__global__ __launch_bounds__(256) void vq_main_fb(const float* __restrict__ z,
                                                  const float* __restrict__ cb,
                                                  const float* __restrict__ cn,
                                                  float* __restrict__ out) {
  __shared__ float zs[FB_BM * FB_LD];
  __shared__ float csh[FB_BK * FB_LD];
  __shared__ float redd[FB_BM][16];
  __shared__ int   redi[FB_BM][16];
  __shared__ int   sidx[FB_BM];
  const int t = threadIdx.x;
  const int row0 = blockIdx.x * FB_BM;
  #pragma unroll
  for (int i = 0; i < 16; ++i) {
    int f = t + i * 256; int r = f >> 6, c4 = f & 63;
    *reinterpret_cast<float4*>(&zs[r * FB_LD + c4 * 4]) =
        *reinterpret_cast<const float4*>(z + (size_t)(row0 + r) * DDIM + c4 * 4);
  }
  const int tr = t >> 4, tc = t & 15;
  float best[4]; int bidx[4];
  #pragma unroll
  for (int i = 0; i < 4; ++i) { best[i] = 3.4e38f; bidx[i] = 0; }
  for (int kt = 0; kt < KCODES; kt += FB_BK) {
    __syncthreads();
    #pragma unroll
    for (int i = 0; i < 8; ++i) {
      int f = t + i * 256; int r = f >> 6, c4 = f & 63;
      *reinterpret_cast<float4*>(&csh[r * FB_LD + c4 * 4]) =
          *reinterpret_cast<const float4*>(cb + (size_t)(kt + r) * DDIM + c4 * 4);
    }
    __syncthreads();
    float acc[4][2] = {{0.f,0.f},{0.f,0.f},{0.f,0.f},{0.f,0.f}};
    #pragma unroll 8
    for (int d4 = 0; d4 < 64; ++d4) {
      float4 b0 = *reinterpret_cast<const float4*>(&csh[tc * FB_LD + d4 * 4]);
      float4 b1v = *reinterpret_cast<const float4*>(&csh[(tc + 16) * FB_LD + d4 * 4]);
      #pragma unroll
      for (int i = 0; i < 4; ++i) {
        float4 a = *reinterpret_cast<const float4*>(&zs[(4 * tr + i) * FB_LD + d4 * 4]);
        acc[i][0] = fmaf(a.x, b0.x, acc[i][0]); acc[i][0] = fmaf(a.y, b0.y, acc[i][0]);
        acc[i][0] = fmaf(a.z, b0.z, acc[i][0]); acc[i][0] = fmaf(a.w, b0.w, acc[i][0]);
        acc[i][1] = fmaf(a.x, b1v.x, acc[i][1]); acc[i][1] = fmaf(a.y, b1v.y, acc[i][1]);
        acc[i][1] = fmaf(a.z, b1v.z, acc[i][1]); acc[i][1] = fmaf(a.w, b1v.w, acc[i][1]);
      }
    }
    float cn0 = cn[kt + tc], cn1 = cn[kt + tc + 16];
    #pragma unroll
    for (int i = 0; i < 4; ++i) {
      float d0 = cn0 - 2.0f * acc[i][0];
      if (d0 < best[i]) { best[i] = d0; bidx[i] = kt + tc; }
      float d1 = cn1 - 2.0f * acc[i][1];
      if (d1 < best[i]) { best[i] = d1; bidx[i] = kt + tc + 16; }
    }
  }
  #pragma unroll
  for (int i = 0; i < 4; ++i) { redd[4 * tr + i][tc] = best[i]; redi[4 * tr + i][tc] = bidx[i]; }
  __syncthreads();
  if (t < FB_BM) {
    float bd = redd[t][0]; int bi = redi[t][0];
    #pragma unroll
    for (int j = 1; j < 16; ++j) {
      float d = redd[t][j]; int ix = redi[t][j];
      if (d < bd || (d == bd && ix < bi)) { bd = d; bi = ix; }
    }
    sidx[t] = bi;
    out[QZ + row0 + t] = (float)bi;
  }
  __syncthreads();
  #pragma unroll
  for (int i = 0; i < 16; ++i) {
    int f = t + i * 256; int r = f >> 6, c4 = f & 63;
    *reinterpret_cast<float4*>(&out[(size_t)(row0 + r) * DDIM + c4 * 4]) =
        *reinterpret_cast<const float4*>(cb + (size_t)sidx[r] * DDIM + c4 * 4);
  }
}

extern "C" void kernel_launch(void* const* d_in, const int* in_sizes, int n_in,
                              void* d_out, int out_size, void* d_ws, size_t ws_size,
                              hipStream_t stream) {
  const float* z  = (const float*)d_in[0];
  const float* cb = (const float*)d_in[1];
  float* out = (float*)d_out;

  const size_t OFF_CN   = (size_t)KCODES * 512;            // 4 MiB wcb
  const size_t OFF_CNT  = OFF_CN + (size_t)KCODES * 4;
  const size_t OFF_RA   = OFF_CNT + 16;
  const size_t OFF_RB   = OFF_RA + (size_t)N_ROWS * 16;
  const size_t OFF_KEYS = OFF_RB + (size_t)N_ROWS * 4;
  const size_t NEED     = OFF_KEYS + (size_t)N_ROWS * 8;

  if (ws_size >= NEED) {
    unsigned char* wcb = (unsigned char*)d_ws;
    float* cn = (float*)(wcb + OFF_CN);
    int* cntA = (int*)(wcb + OFF_CNT);
    int* cntB = (int*)(wcb + OFF_CNT + 4);
    int4* rowsA = (int4*)(wcb + OFF_RA);
    int* rowsB = (int*)(wcb + OFF_RB);
    unsigned long long* keysB = (unsigned long long*)(wcb + OFF_KEYS);
    hipMemsetAsync(cntA, 0, 8, stream);
    hipMemsetAsync(keysB, 0xFF, (size_t)N_ROWS * 8, stream);
    vq_prep<<<KCODES / 4, 256, 0, stream>>>(cb, wcb, cn);
    vq_mfma<<<N_ROWS / 64, 256, 0, stream>>>(z, wcb, cn, cb, out,
                                             cntA, rowsA, cntB, rowsB);
    vq_pairs<<<128, 256, 0, stream>>>(z, cb, cn, out, cntA, rowsA);
    vq_fullsweep<<<256, 256, 0, stream>>>(z, cb, cn, cntB, rowsB, keysB);
    vq_finishB<<<64, 256, 0, stream>>>(cb, out, cntB, rowsB, keysB);
  } else {
    float* cn = (float*)d_ws;
    vq_cnorm<<<KCODES / 4, 256, 0, stream>>>(cb, cn);
    vq_main_fb<<<N_ROWS / FB_BM, 256, 0, stream>>>(z, cb, cn, out);
  }
}

// Round 8
// 431.491 us; speedup vs baseline: 2.4647x; 1.1038x over previous
//
#include <hip/hip_runtime.h>
#include <hip/hip_bf16.h>

#define N_ROWS 32768
#define DDIM   256
#define KCODES 8192
#define QZ     (N_ROWS * DDIM)
#define NT_W   256            // tiles per wave: 4096 codes / 16
#define MARGIN 0.8f           // ~6+ sigma of hi*hi approx-error diff (passed 2x)

typedef __attribute__((ext_vector_type(8))) short short8;
typedef __attribute__((ext_vector_type(4))) float f32x4;

__device__ __forceinline__ unsigned short f2bf(float f) {   // RNE float->bf16
  unsigned u = __builtin_bit_cast(unsigned, f);
  u += 0x7FFFu + ((u >> 16) & 1u);
  return (unsigned short)(u >> 16);
}

// insert distance d (code c) into per-row top-3 state (b1<=b2<=b3)
__device__ __forceinline__ void ins(float& b1, float& b2, float& b3, int& i1, int& i2,
                                    float d, int c) {
  bool l3 = d < b3, l2 = d < b2, l1 = d < b1;
  b3 = l3 ? (l2 ? b2 : d) : b3;
  b2 = l2 ? (l1 ? b1 : d) : b2;
  i2 = l2 ? (l1 ? i1 : c) : i2;
  b1 = l1 ? d : b1;
  i1 = l1 ? c : i1;
}

// merge sorted triple (o1<=o2<=o3, idx y1,y2) into (a1<=a2<=a3, idx x1,x2)
__device__ __forceinline__ void merge3(float& a1, float& a2, float& a3, int& x1, int& x2,
                                       float o1, float o2, float o3, int y1, int y2) {
  bool oW = o1 < a1;
  float mx1 = oW ? a1 : o1;  int mxi = oW ? x1 : y1;
  float n1  = oW ? o1 : a1;  int ni1 = oW ? y1 : x1;
  bool lA = a2 < o2;
  float lo2 = lA ? a2 : o2;  int li2 = lA ? x2 : y2;
  float hi2 = lA ? o2 : a2;
  bool m2w = mx1 < lo2;
  float n2 = m2w ? mx1 : lo2; int ni2 = m2w ? mxi : li2;
  float n3 = fminf(fminf(fmaxf(mx1, lo2), hi2), fminf(a3, o3));
  a1 = n1; a2 = n2; a3 = n3; x1 = ni1; x2 = ni2;
}

// ---- cnorm only (fallback path) ----
__global__ __launch_bounds__(256) void vq_cnorm(const float* __restrict__ cb,
                                                float* __restrict__ cn) {
  int n = blockIdx.x * 4 + (threadIdx.x >> 6);
  int lane = threadIdx.x & 63;
  float4 c4 = *reinterpret_cast<const float4*>(cb + (size_t)n * DDIM + lane * 4);
  double s = (double)c4.x * c4.x + (double)c4.y * c4.y +
             (double)c4.z * c4.z + (double)c4.w * c4.w;
  #pragma unroll
  for (int off = 32; off > 0; off >>= 1) s += __shfl_down(s, off, 64);
  if (lane == 0) cn[n] = (float)s;
}

// ---- prep: codebook -> bf16 HI, UNIT-MAJOR within 16-code groups + cnorm ----
// byte offset of (code n, 16B unit u): (n>>4)*8192 + u*256 + (n&15)*16
// -> a wave loading 16 codes x one dc-group reads contiguous 1KB (perfect coalesce)
__global__ __launch_bounds__(256) void vq_prep(const float* __restrict__ cb,
                                               unsigned char* __restrict__ wcb,
                                               float* __restrict__ cn) {
  int n = blockIdx.x * 4 + (threadIdx.x >> 6);
  int lane = threadIdx.x & 63;
  float4 c4 = *reinterpret_cast<const float4*>(cb + (size_t)n * DDIM + lane * 4);
  double s = (double)c4.x * c4.x + (double)c4.y * c4.y +
             (double)c4.z * c4.z + (double)c4.w * c4.w;
  #pragma unroll
  for (int off = 32; off > 0; off >>= 1) s += __shfl_down(s, off, 64);
  if (lane == 0) cn[n] = (float)s;

  unsigned short h0 = f2bf(c4.x), h1 = f2bf(c4.y), h2 = f2bf(c4.z), h3 = f2bf(c4.w);
  // lane covers logical bytes [8*lane, 8*lane+8): unit = lane>>1, half = lane&1
  size_t base = (size_t)(n >> 4) * 8192 + (size_t)(lane >> 1) * 256 +
                (size_t)(n & 15) * 16 + (size_t)(lane & 1) * 8;
  *reinterpret_cast<ushort4*>(wcb + base) = make_ushort4(h0, h1, h2, h3);
}

// ---- main MFMA kernel: 512 blocks x 256 thr (4 waves); block = 64 rows ----
// Wave (wm, wh): rows [blk*64 + wm*32, +32), codes [wh*4096, +4096).
// B fragments are lane-private -> loaded straight from L2 to registers,
// double-buffered. NO LDS staging, NO barriers in the K-loop.
__global__ __launch_bounds__(256, 2) void vq_mfma(
    const float* __restrict__ z, const unsigned char* __restrict__ wcb,
    const float* __restrict__ cn, const float* __restrict__ cb,
    float* __restrict__ out,
    int* __restrict__ cntA, int4* __restrict__ rowsA,
    int* __restrict__ cntB, int* __restrict__ rowsB) {
  __shared__ float rb1[2][64], rb2[2][64], rb3[2][64];
  __shared__ int   ri1[2][64], ri2[2][64];
  __shared__ int   sIdx[64];

  const int tid = threadIdx.x;
  const int w = tid >> 6, lane = tid & 63;
  const int wm = w >> 1, wh = w & 1;
  const int g = lane >> 4, l15 = lane & 15;

  // A fragments: hi-only bf16, 2 mfrags x 8 dc = 64 VGPR, resident whole kernel
  short8 zh[2][8];
  const int rA = blockIdx.x * 64 + wm * 32 + l15;
  #pragma unroll
  for (int mf = 0; mf < 2; ++mf) {
    #pragma unroll
    for (int dc = 0; dc < 8; ++dc) {
      const float* zp = z + (size_t)(rA + mf * 16) * DDIM + dc * 32 + g * 8;
      float4 f0 = *reinterpret_cast<const float4*>(zp);
      float4 f1 = *reinterpret_cast<const float4*>(zp + 4);
      short8 hh;
      hh[0] = (short)f2bf(f0.x); hh[1] = (short)f2bf(f0.y);
      hh[2] = (short)f2bf(f0.z); hh[3] = (short)f2bf(f0.w);
      hh[4] = (short)f2bf(f1.x); hh[5] = (short)f2bf(f1.y);
      hh[6] = (short)f2bf(f1.z); hh[7] = (short)f2bf(f1.w);
      zh[mf][dc] = hh;
    }
  }

  // per-row-slot top-3 (8 slots = 2 mf x 4 acc rows)
  float b1[8], b2[8], b3[8];
  int i1[8], i2[8];
  #pragma unroll
  for (int s = 0; s < 8; ++s) { b1[s] = 3.4e38f; b2[s] = 3.4e38f; b3[s] = 3.4e38f; i1[s] = 0; i2[s] = 0; }

  // B stream base: wave's half of wcb; tile nt = 16 codes = 8KB, lane-linear
  const short8* bp = reinterpret_cast<const short8*>(wcb) +
                     ((size_t)(wh * 256) * 512) + lane;
  const int ccbase = wh * 4096 + l15;

#define LOADT(dst, nt_) do {                                         \
    const short8* tp = bp + ((size_t)(nt_) * 512);                   \
    _Pragma("unroll")                                                \
    for (int i_ = 0; i_ < 8; ++i_) dst[i_] = tp[i_ * 64];            \
  } while (0)

#define COMPT(B_, nt_) do {                                          \
    const int cc_ = ccbase + (nt_) * 16;                             \
    const float cnv_ = cn[cc_];                                      \
    f32x4 a0_ = {0.f, 0.f, 0.f, 0.f}, a1_ = a0_;                     \
    _Pragma("unroll")                                                \
    for (int dc_ = 0; dc_ < 8; ++dc_) {                              \
      a0_ = __builtin_amdgcn_mfma_f32_16x16x32_bf16(zh[0][dc_], B_[dc_], a0_, 0, 0, 0); \
      a1_ = __builtin_amdgcn_mfma_f32_16x16x32_bf16(zh[1][dc_], B_[dc_], a1_, 0, 0, 0); \
    }                                                                \
    _Pragma("unroll")                                                \
    for (int r_ = 0; r_ < 4; ++r_) {                                 \
      float d0_ = fmaf(-2.0f, a0_[r_], cnv_);                        \
      ins(b1[r_], b2[r_], b3[r_], i1[r_], i2[r_], d0_, cc_);         \
      float d1_ = fmaf(-2.0f, a1_[r_], cnv_);                        \
      ins(b1[4 + r_], b2[4 + r_], b3[4 + r_], i1[4 + r_], i2[4 + r_], d1_, cc_); \
    }                                                                \
  } while (0)

  short8 Ba[8], Bb[8];
  LOADT(Ba, 0);
  for (int nt = 0; nt < NT_W; nt += 2) {
    LOADT(Bb, nt + 1);                 // prefetch odd tile
    COMPT(Ba, nt);
    if (nt + 2 < NT_W) LOADT(Ba, nt + 2);   // prefetch next even tile
    COMPT(Bb, nt + 1);
  }
#undef LOADT
#undef COMPT

  // intra-wave merge across the 16 code-lanes
  #pragma unroll
  for (int s = 0; s < 8; ++s) {
    float B1 = b1[s], B2 = b2[s], B3 = b3[s];
    int I1 = i1[s], I2 = i2[s];
    #pragma unroll
    for (int m = 1; m <= 8; m <<= 1) {
      float o1 = __shfl_xor(B1, m, 64), o2 = __shfl_xor(B2, m, 64), o3 = __shfl_xor(B3, m, 64);
      int y1 = __shfl_xor(I1, m, 64), y2 = __shfl_xor(I2, m, 64);
      merge3(B1, B2, B3, I1, I2, o1, o2, o3, y1, y2);
    }
    if (l15 == 0) {
      int row = wm * 32 + (s >> 2) * 16 + g * 4 + (s & 3);
      rb1[wh][row] = B1; rb2[wh][row] = B2; rb3[wh][row] = B3;
      ri1[wh][row] = I1; ri2[wh][row] = I2;
    }
  }
  __syncthreads();

  // merge the 2 wh copies, write index, flag tight rows
  if (tid < 64) {
    float B1 = rb1[0][tid], B2 = rb2[0][tid], B3 = rb3[0][tid];
    int I1 = ri1[0][tid], I2 = ri2[0][tid];
    merge3(B1, B2, B3, I1, I2, rb1[1][tid], rb2[1][tid], rb3[1][tid], ri1[1][tid], ri2[1][tid]);
    int grow = blockIdx.x * 64 + tid;
    out[QZ + grow] = (float)I1;
    sIdx[tid] = I1;
    if (B3 - B1 < MARGIN) {                    // >2 contenders: full exact sweep
      int p = atomicAdd(cntB, 1);
      rowsB[p] = grow;
    } else if (B2 - B1 < MARGIN) {             // 2 contenders: exact pair check
      int p = atomicAdd(cntA, 1);
      rowsA[p] = make_int4(grow, I1, I2, 0);
    }
  }
  __syncthreads();

  // gather q_z = codebook[idx]: 64 rows x 64 float4
  #pragma unroll
  for (int i = 0; i < 16; ++i) {
    int f = tid + i * 256;
    int r = f >> 6, c4i = f & 63;
    float4 v = *reinterpret_cast<const float4*>(cb + (size_t)sIdx[r] * DDIM + c4i * 4);
    *reinterpret_cast<float4*>(&out[(size_t)(blockIdx.x * 64 + r) * DDIM + c4i * 4]) = v;
  }
}

// ---- cleanup A: exact fp32 compare of top-2 candidates per flagged row ----
__global__ __launch_bounds__(256) void vq_pairs(
    const float* __restrict__ z, const float* __restrict__ cb, const float* __restrict__ cn,
    float* __restrict__ out, const int* __restrict__ cntA, const int4* __restrict__ rowsA) {
  int n = *cntA;
  int lane = threadIdx.x & 63;
  for (int e = blockIdx.x * 4 + (threadIdx.x >> 6); e < n; e += gridDim.x * 4) {
    int4 ent = rowsA[e];
    int row = ent.x, c1 = ent.y, c2 = ent.z;
    float4 zv = *reinterpret_cast<const float4*>(z + (size_t)row * DDIM + lane * 4);
    float4 a = *reinterpret_cast<const float4*>(cb + (size_t)c1 * DDIM + lane * 4);
    float4 b = *reinterpret_cast<const float4*>(cb + (size_t)c2 * DDIM + lane * 4);
    float p1 = zv.x * a.x + zv.y * a.y + zv.z * a.z + zv.w * a.w;
    float p2 = zv.x * b.x + zv.y * b.y + zv.z * b.z + zv.w * b.w;
    #pragma unroll
    for (int m = 1; m <= 32; m <<= 1) { p1 += __shfl_xor(p1, m, 64); p2 += __shfl_xor(p2, m, 64); }
    float d1 = cn[c1] - 2.0f * p1;
    float d2 = cn[c2] - 2.0f * p2;
    int win = (d2 < d1 || (d2 == d1 && c2 < c1)) ? c2 : c1;
    if (lane == 0) out[QZ + row] = (float)win;
    float4 cw = *reinterpret_cast<const float4*>(cb + (size_t)win * DDIM + lane * 4);
    *reinterpret_cast<float4*>(&out[(size_t)row * DDIM + lane * 4]) = cw;
  }
}

// ---- cleanup B: exact fp32 full-codebook argmin, LDS-staged chunk x row-loop ----
#define FS_CODES 128
#define FS_PAD   257
__global__ __launch_bounds__(256) void vq_fullsweep(
    const float* __restrict__ z, const float* __restrict__ cb, const float* __restrict__ cn,
    const int* __restrict__ cntB, const int* __restrict__ rowsB,
    unsigned long long* __restrict__ keysB) {
  __shared__ float csL[FS_CODES * FS_PAD];   // ~131.6 KB
  __shared__ float zr[DDIM];
  __shared__ float part[4][FS_CODES];
  const int nB = *cntB;
  if (nB == 0) return;
  const int cid = blockIdx.x & 63;           // code chunk
  const int sid = blockIdx.x >> 6;           // row split (0..3)
  const int t = threadIdx.x;
  const int q = t >> 6, k = t & 63;

  const float* src = cb + (size_t)cid * FS_CODES * DDIM;
  #pragma unroll
  for (int i = 0; i < 32; ++i) {
    int f = t + i * 256;
    int code = f >> 6, j = f & 63;
    float4 v = *reinterpret_cast<const float4*>(src + (size_t)f * 4);
    *reinterpret_cast<float4*>(&csL[code * FS_PAD + j * 4]) = v;
  }
  float cnk = (t < FS_CODES) ? cn[cid * FS_CODES + t] : 0.f;

  for (int r = sid; r < nB; r += 4) {
    const int row = rowsB[r];
    __syncthreads();
    if (t < 64)
      *reinterpret_cast<float4*>(&zr[t * 4]) =
          *reinterpret_cast<const float4*>(z + (size_t)row * DDIM + t * 4);
    __syncthreads();

    float acc0 = 0.f, acc1 = 0.f;
    #pragma unroll
    for (int j = 0; j < 16; ++j) {
      float4 a  = *reinterpret_cast<const float4*>(&zr[q * 64 + j * 4]);
      float4 c0 = *reinterpret_cast<const float4*>(&csL[k * FS_PAD + q * 64 + j * 4]);
      float4 c1 = *reinterpret_cast<const float4*>(&csL[(k + 64) * FS_PAD + q * 64 + j * 4]);
      acc0 = fmaf(a.x, c0.x, acc0); acc0 = fmaf(a.y, c0.y, acc0);
      acc0 = fmaf(a.z, c0.z, acc0); acc0 = fmaf(a.w, c0.w, acc0);
      acc1 = fmaf(a.x, c1.x, acc1); acc1 = fmaf(a.y, c1.y, acc1);
      acc1 = fmaf(a.z, c1.z, acc1); acc1 = fmaf(a.w, c1.w, acc1);
    }
    part[q][k] = acc0;
    part[q][k + 64] = acc1;
    __syncthreads();

    if (t < FS_CODES) {
      float dot = part[0][t] + part[1][t] + part[2][t] + part[3][t];
      float d = cnk - 2.0f * dot;
      int code = cid * FS_CODES + t;
      unsigned m = __builtin_bit_cast(unsigned, d);
      m = (m >> 31) ? ~m : (m | 0x80000000u);
      unsigned long long key = ((unsigned long long)m << 32) | (unsigned)code;
      #pragma unroll
      for (int mm = 1; mm <= 32; mm <<= 1) {
        unsigned long long o = __shfl_xor(key, mm, 64);
        key = (o < key) ? o : key;
      }
      if (k == 0) atomicMin(&keysB[r], key);
    }
  }
}

// ---- finish B: write index + gather for full-swept rows ----
__global__ __launch_bounds__(256) void vq_finishB(
    const float* __restrict__ cb, float* __restrict__ out,
    const int* __restrict__ cntB, const int* __restrict__ rowsB,
    const unsigned long long* __restrict__ keysB) {
  int nB = *cntB;
  int lane = threadIdx.x & 63;
  for (int e = blockIdx.x * 4 + (threadIdx.x >> 6); e < nB; e += gridDim.x * 4) {
    int row = rowsB[e];
    int idx = (int)(keysB[e] & 0xFFFFFFFFULL);
    if (lane == 0) out[QZ + row] = (float)idx;
    *reinterpret_cast<float4*>(&out[(size_t)row * DDIM + lane * 4]) =
        *reinterpret_cast<const float4*>(cb + (size_t)idx * DDIM + lane * 4);
  }
}

// ---- round-1 fp32 fallback (only if ws too small) ----
#define FB_BM 64
#define FB_BK 32
#define FB_LD 260
__global__ __launch_bounds__(256) void vq_main_fb(const float* __restrict__ z,
                                                  const float* __restrict__ cb,
                                                  const float* __restrict__ cn,
                                                  float* __restrict__ out) {
  __shared__ float zs[FB_BM * FB_LD];
  __shared__ float csh[FB_BK * FB_LD];
  __shared__ float redd[FB_BM][16];
  __shared__ int   redi[FB_BM][16];
  __shared__ int   sidx[FB_BM];
  const int t = threadIdx.x;
  const int row0 = blockIdx.x * FB_BM;
  #pragma unroll
  for (int i = 0; i < 16; ++i) {
    int f = t + i * 256; int r = f >> 6, c4 = f & 63;
    *reinterpret_cast<float4*>(&zs[r * FB_LD + c4 * 4]) =
        *reinterpret_cast<const float4*>(z + (size_t)(row0 + r) * DDIM + c4 * 4);
  }
  const int tr = t >> 4, tc = t & 15;
  float best[4]; int bidx[4];
  #pragma unroll
  for (int i = 0; i < 4; ++i) { best[i] = 3.4e38f; bidx[i] = 0; }
  for (int kt = 0; kt < KCODES; kt += FB_BK) {
    __syncthreads();
    #pragma unroll
    for (int i = 0; i < 8; ++i) {
      int f = t + i * 256; int r = f >> 6, c4 = f & 63;
      *reinterpret_cast<float4*>(&csh[r * FB_LD + c4 * 4]) =
          *reinterpret_cast<const float4*>(cb + (size_t)(kt + r) * DDIM + c4 * 4);
    }
    __syncthreads();
    float acc[4][2] = {{0.f,0.f},{0.f,0.f},{0.f,0.f},{0.f,0.f}};
    #pragma unroll 8
    for (int d4 = 0; d4 < 64; ++d4) {
      float4 b0 = *reinterpret_cast<const float4*>(&csh[tc * FB_LD + d4 * 4]);
      float4 b1v = *reinterpret_cast<const float4*>(&csh[(tc + 16) * FB_LD + d4 * 4]);
      #pragma unroll
      for (int i = 0; i < 4; ++i) {
        float4 a = *reinterpret_cast<const float4*>(&zs[(4 * tr + i) * FB_LD + d4 * 4]);
        acc[i][0] = fmaf(a.x, b0.x, acc[i][0]); acc[i][0] = fmaf(a.y, b0.y, acc[i][0]);
        acc[i][0] = fmaf(a.z, b0.z, acc[i][0]); acc[i][0] = fmaf(a.w, b0.w, acc[i][0]);
        acc[i][1] = fmaf(a.x, b1v.x, acc[i][1]); acc[i][1] = fmaf(a.y, b1v.y, acc[i][1]);
        acc[i][1] = fmaf(a.z, b1v.z, acc[i][1]); acc[i][1] = fmaf(a.w, b1v.w, acc[i][1]);
      }
    }
    float cn0 = cn[kt + tc], cn1 = cn[kt + tc + 16];
    #pragma unroll
    for (int i = 0; i < 4; ++i) {
      float d0 = cn0 - 2.0f * acc[i][0];
      if (d0 < best[i]) { best[i] = d0; bidx[i] = kt + tc; }
      float d1 = cn1 - 2.0f * acc[i][1];
      if (d1 < best[i]) { best[i] = d1; bidx[i] = kt + tc + 16; }
    }
  }
  #pragma unroll
  for (int i = 0; i < 4; ++i) { redd[4 * tr + i][tc] = best[i]; redi[4 * tr + i][tc] = bidx[i]; }
  __syncthreads();
  if (t < FB_BM) {
    float bd = redd[t][0]; int bi = redi[t][0];
    #pragma unroll
    for (int j = 1; j < 16; ++j) {
      float d = redd[t][j]; int ix = redi[t][j];
      if (d < bd || (d == bd && ix < bi)) { bd = d; bi = ix; }
    }
    sidx[t] = bi;
    out[QZ + row0 + t] = (float)bi;
  }
  __syncthreads();
  #pragma unroll
  for (int i = 0; i < 16; ++i) {
    int f = t + i * 256; int r = f >> 6, c4 = f & 63;
    *reinterpret_cast<float4*>(&out[(size_t)(row0 + r) * DDIM + c4 * 4]) =
        *reinterpret_cast<const float4*>(cb + (size_t)sidx[r] * DDIM + c4 * 4);
  }
}

extern "C" void kernel_launch(void* const* d_in, const int* in_sizes, int n_in,
                              void* d_out, int out_size, void* d_ws, size_t ws_size,
                              hipStream_t stream) {
  const float* z  = (const float*)d_in[0];
  const float* cb = (const float*)d_in[1];
  float* out = (float*)d_out;

  const size_t OFF_CN   = (size_t)KCODES * 512;            // 4 MiB wcb
  const size_t OFF_CNT  = OFF_CN + (size_t)KCODES * 4;
  const size_t OFF_RA   = OFF_CNT + 16;
  const size_t OFF_RB   = OFF_RA + (size_t)N_ROWS * 16;
  const size_t OFF_KEYS = OFF_RB + (size_t)N_ROWS * 4;
  const size_t NEED     = OFF_KEYS + (size_t)N_ROWS * 8;

  if (ws_size >= NEED) {
    unsigned char* wcb = (unsigned char*)d_ws;
    float* cn = (float*)(wcb + OFF_CN);
    int* cntA = (int*)(wcb + OFF_CNT);
    int* cntB = (int*)(wcb + OFF_CNT + 4);
    int4* rowsA = (int4*)(wcb + OFF_RA);
    int* rowsB = (int*)(wcb + OFF_RB);
    unsigned long long* keysB = (unsigned long long*)(wcb + OFF_KEYS);
    hipMemsetAsync(cntA, 0, 8, stream);
    hipMemsetAsync(keysB, 0xFF, (size_t)N_ROWS * 8, stream);
    vq_prep<<<KCODES / 4, 256, 0, stream>>>(cb, wcb, cn);
    vq_mfma<<<N_ROWS / 64, 256, 0, stream>>>(z, wcb, cn, cb, out,
                                             cntA, rowsA, cntB, rowsB);
    vq_pairs<<<128, 256, 0, stream>>>(z, cb, cn, out, cntA, rowsA);
    vq_fullsweep<<<256, 256, 0, stream>>>(z, cb, cn, cntB, rowsB, keysB);
    vq_finishB<<<64, 256, 0, stream>>>(cb, out, cntB, rowsB, keysB);
  } else {
    float* cn = (float*)d_ws;
    vq_cnorm<<<KCODES / 4, 256, 0, stream>>>(cb, cn);
    vq_main_fb<<<N_ROWS / FB_BM, 256, 0, stream>>>(z, cb, cn, out);
  }
}